// Round 14
// baseline (297.416 us; speedup 1.0000x reference)
//
#include <hip/hip_runtime.h>
#include <stdint.h>

// Shapes (fixed): B=4, S=2048, D=1024, H=16, DH=64
#define NB 4
#define NS 2048
#define ND 1024
#define NH 16
#define NDH 64

typedef __attribute__((ext_vector_type(8))) short bf16x8;
typedef __attribute__((ext_vector_type(4))) float f32x4;

#define MFMA16(a, b, c) __builtin_amdgcn_mfma_f32_16x16x32_bf16((a), (b), (c), 0, 0, 0)

__device__ __forceinline__ uint16_t f2bf(float f) {
  uint32_t u = __builtin_bit_cast(uint32_t, f);
  return (uint16_t)((u + 0x7FFFu + ((u >> 16) & 1u)) >> 16);
}

// truncating bf16x2 pack / unpack (for partial-sum shipping; bias negligible on partials)
__device__ __forceinline__ uint32_t pk2(float lo, float hi) {
  return (__builtin_bit_cast(uint32_t, hi) & 0xFFFF0000u) |
         (__builtin_bit_cast(uint32_t, lo) >> 16);
}
__device__ __forceinline__ float unlo(uint32_t u) { return __builtin_bit_cast(float, u << 16); }
__device__ __forceinline__ float unhi(uint32_t u) { return __builtin_bit_cast(float, u & 0xFFFF0000u); }

__device__ __forceinline__ void gload_lds16(const void* g, void* l) {
  __builtin_amdgcn_global_load_lds(
      (const __attribute__((address_space(1))) uint32_t*)(uintptr_t)g,
      (__attribute__((address_space(3))) uint32_t*)(uintptr_t)l, 16, 0, 0);
}

// ---------------- fp32 -> bf16 convert (x) ----------------
__global__ __launch_bounds__(256) void cvt_bf16_kernel(const float* __restrict__ src,
                                                       uint16_t* __restrict__ dst, int n4) {
  int i = blockIdx.x * 256 + threadIdx.x;
  if (i >= n4) return;
  const float4 f = *(const float4*)(src + (size_t)i * 4);
  union { uint16_t u[4]; uint64_t q; } o;
  o.u[0] = f2bf(f.x); o.u[1] = f2bf(f.y); o.u[2] = f2bf(f.z); o.u[3] = f2bf(f.w);
  *(uint64_t*)(dst + (size_t)i * 4) = o.q;
}

// ---------------- transpose + convert: W[1024][1024] f32 -> Wt[n][k] bf16 ----------------
__global__ __launch_bounds__(256) void transpose_cvt(const float* __restrict__ W,
                                                     uint16_t* __restrict__ Wt) {
  __shared__ uint16_t tile[32][33];
  const int bx = blockIdx.x * 32;  // n
  const int by = blockIdx.y * 32;  // k
  const int tx = threadIdx.x;      // 0..31
  const int ty = threadIdx.y;      // 0..7
#pragma unroll
  for (int j = 0; j < 4; j++)
    tile[ty + j * 8][tx] = f2bf(W[(size_t)(by + ty + j * 8) * 1024 + bx + tx]);
  __syncthreads();
#pragma unroll
  for (int j = 0; j < 4; j++)
    Wt[(size_t)(bx + ty + j * 8) * 1024 + by + tx] = tile[tx][ty + j * 8];
}

// ---------------- GEMM: C[M][c] = A[M][K=1024] * Wt[c][K=1024]^T ----------------
// MODE 0: QKV projection, N=3072, scatter to Q [BH][S][64], K [BH][S][64], Vt [BH][64][S] (bf16)
// MODE 1: out projection, N=1024, write fp32 C row-major
template <int MODE>
__global__ __launch_bounds__(256) void gemm_bt(const uint16_t* __restrict__ A,
                                               const uint16_t* __restrict__ Bt,
                                               uint16_t* __restrict__ O0,
                                               uint16_t* __restrict__ O1,
                                               uint16_t* __restrict__ O2,
                                               float* __restrict__ OF) {
  __shared__ uint16_t lds[2][128 * 32];  // [0]=A tile [128][32], [1]=B tile [128][32]
  const int tid = threadIdx.x;
  const int lane = tid & 63;
  const int wave = tid >> 6;
  const int wr = wave >> 1, wc = wave & 1;
  const int l15 = lane & 15, lg = lane >> 4;
  const int row0 = blockIdx.y * 128;
  const int col0 = blockIdx.x * 128;

  f32x4 acc[4][4];
#pragma unroll
  for (int i = 0; i < 4; i++)
#pragma unroll
    for (int j = 0; j < 4; j++) acc[i][j] = f32x4{0.f, 0.f, 0.f, 0.f};

  const int srow = tid >> 2;          // 0..63
  const int scb = (tid & 3) * 16;     // byte offset within 64B row
  const char* Ab = (const char*)A;
  const char* Bb = (const char*)Bt;
  char* ldsA = (char*)&lds[0][0];
  char* ldsB = (char*)&lds[1][0];
  const int wbase = wave * 1024;      // wave-uniform LDS offset (HW adds lane*16)

  for (int kt = 0; kt < 1024; kt += 32) {
#pragma unroll
    for (int j = 0; j < 2; ++j) {
      const int r = j * 64 + srow;
      gload_lds16(Ab + ((size_t)(row0 + r) * 1024 + kt) * 2 + scb, ldsA + j * 4096 + wbase);
      gload_lds16(Bb + ((size_t)(col0 + r) * 1024 + kt) * 2 + scb, ldsB + j * 4096 + wbase);
    }
    __syncthreads();
    bf16x8 bfr[4];
#pragma unroll
    for (int ni = 0; ni < 4; ni++)
      bfr[ni] = *(const bf16x8*)&lds[1][(wc * 64 + ni * 16 + l15) * 32 + lg * 8];
#pragma unroll
    for (int mi = 0; mi < 4; mi++) {
      const bf16x8 afr = *(const bf16x8*)&lds[0][(wr * 64 + mi * 16 + l15) * 32 + lg * 8];
#pragma unroll
      for (int ni = 0; ni < 4; ni++) acc[mi][ni] = MFMA16(afr, bfr[ni], acc[mi][ni]);
    }
    __syncthreads();
  }

  // Epilogue. C/D layout: col = lane&15, row = (lane>>4)*4 + i  [m89-verified]
#pragma unroll
  for (int mi = 0; mi < 4; mi++) {
#pragma unroll
    for (int ni = 0; ni < 4; ni++) {
      const int c = col0 + wc * 64 + ni * 16 + l15;
      const int rbase = row0 + wr * 64 + mi * 16 + lg * 4;
#pragma unroll
      for (int i = 0; i < 4; i++) {
        const int r = rbase + i;
        const float v = acc[mi][ni][i];
        if (MODE == 0) {
          const int which = c >> 10, cc = c & 1023;
          const int h = cc >> 6, dh = cc & 63;
          const int b = r >> 11, s = r & 2047;
          const size_t hb = (size_t)(b * NH + h);
          if (which == 0)
            O0[(hb * NS + s) * 64 + dh] = f2bf(v * 0.18033688011112042f);  // (1/8)*log2(e)
          else if (which == 1)
            O1[(hb * NS + s) * 64 + dh] = f2bf(v);
          else
            O2[(hb * 64 + dh) * NS + s] = f2bf(v);
        } else {
          OF[(size_t)r * 1024 + c] = v;
        }
      }
    }
  }
}

// ---- partial attention segment: tiles [t0, t1) of 32-row unit u (rows [32u, 32u+32))
// of head bh. Dual 16-row chains A/B (ILP-2, unconditional). No-max softmax: P=exp2(s),
// masked -> 0 (only reachable when t==tmax, i.e. in second-half segments).
// Accumulates into caller's oA/oB/rsA/rsB (pure sums -> split-KV is exact).
__device__ __forceinline__ void attn_seg(const uint16_t* __restrict__ Qh,
                                         const uint16_t* __restrict__ Kh,
                                         const uint16_t* __restrict__ Vh,
                                         int u, int t0, int t1, int l15, int lg,
                                         uint16_t (*pw)[16][68],
                                         f32x4* oA, f32x4* oB, f32x4& rsA, f32x4& rsB) {
  const int qbA = u * 32;
  const int qbB = qbA + 16;
  const int tmax = u >> 1;
  const int nfdA = (2 * u) & 3;  // 0 or 2
  const int nfdB = nfdA + 1;

  const bf16x8 qfA0 = *(const bf16x8*)&Qh[(size_t)(qbA + l15) * 64 + lg * 8];
  const bf16x8 qfA1 = *(const bf16x8*)&Qh[(size_t)(qbA + l15) * 64 + 32 + lg * 8];
  const bf16x8 qfB0 = *(const bf16x8*)&Qh[(size_t)(qbB + l15) * 64 + lg * 8];
  const bf16x8 qfB1 = *(const bf16x8*)&Qh[(size_t)(qbB + l15) * 64 + 32 + lg * 8];

  const short one_bf = (short)0x3F80;  // bf16 1.0
  const bf16x8 ones = {one_bf, one_bf, one_bf, one_bf, one_bf, one_bf, one_bf, one_bf};

  for (int t = t0; t < t1; ++t) {
    // prefetch V fragments for this tile (shared by both chains)
    bf16x8 vr[4][2];
#pragma unroll
    for (int df = 0; df < 4; ++df) {
      const uint16_t* vp = &Vh[(size_t)(df * 16 + l15) * NS + t * 64 + lg * 8];
      vr[df][0] = *(const bf16x8*)vp;
      vr[df][1] = *(const bf16x8*)(vp + 32);
    }
    const int nfmA = (t == tmax) ? nfdA : 3;
    const int nfmB = (t == tmax) ? nfdB : 3;
#pragma unroll
    for (int nf = 0; nf < 4; ++nf) {
      if (nf <= nfmB) {
        const uint16_t* kp = &Kh[(size_t)(t * 64 + nf * 16 + l15) * 64 + lg * 8];
        const bf16x8 k0 = *(const bf16x8*)kp;
        const bf16x8 k1 = *(const bf16x8*)(kp + 32);
        f32x4 a = f32x4{0.f, 0.f, 0.f, 0.f};
        a = MFMA16(qfB0, k0, a);
        a = MFMA16(qfB1, k1, a);
        if (t == tmax && nf == nfdB) {  // chain-B diagonal fragment: mask col > row
#pragma unroll
          for (int i = 0; i < 4; i++)
            if (l15 > lg * 4 + i) a[i] = -1e30f;
        }
#pragma unroll
        for (int i = 0; i < 4; i++)
          pw[1][lg * 4 + i][nf * 16 + l15] = f2bf(exp2f(a[i]));
        if (nf <= nfmA) {
          f32x4 c = f32x4{0.f, 0.f, 0.f, 0.f};
          c = MFMA16(qfA0, k0, c);
          c = MFMA16(qfA1, k1, c);
          if (t == tmax && nf == nfdA) {
#pragma unroll
            for (int i = 0; i < 4; i++)
              if (l15 > lg * 4 + i) c[i] = -1e30f;
          }
#pragma unroll
          for (int i = 0; i < 4; i++)
            pw[0][lg * 4 + i][nf * 16 + l15] = f2bf(exp2f(c[i]));
        } else {
#pragma unroll
          for (int i = 0; i < 4; i++)
            pw[0][lg * 4 + i][nf * 16 + l15] = 0;
        }
      } else {
#pragma unroll
        for (int i = 0; i < 4; i++) {
          pw[0][lg * 4 + i][nf * 16 + l15] = 0;
          pw[1][lg * 4 + i][nf * 16 + l15] = 0;
        }
      }
    }
    // P fragments (C-layout -> A-layout via wave-private LDS; RAW ordered by waitcnt)
    const bf16x8 paA0 = *(const bf16x8*)&pw[0][l15][lg * 8];
    const bf16x8 paA1 = *(const bf16x8*)&pw[0][l15][32 + lg * 8];
    const bf16x8 paB0 = *(const bf16x8*)&pw[1][l15][lg * 8];
    const bf16x8 paB1 = *(const bf16x8*)&pw[1][l15][32 + lg * 8];
    rsA = MFMA16(paA0, ones, rsA);
    rsA = MFMA16(paA1, ones, rsA);
    rsB = MFMA16(paB0, ones, rsB);
    rsB = MFMA16(paB1, ones, rsB);
#pragma unroll
    for (int df = 0; df < 4; ++df) {
      oA[df] = MFMA16(paA0, vr[df][0], oA[df]);
      oA[df] = MFMA16(paA1, vr[df][1], oA[df]);
      oB[df] = MFMA16(paB0, vr[df][0], oB[df]);
      oB[df] = MFMA16(paB1, vr[df][1], oB[df]);
    }
  }
}

// ---------------- causal flash attention (split-KV halves + in-block combine) ----------------
// Legal because no-max softmax makes o and rs PURE SUMS: out = (o1+o2)/(rs1+rs2).
// grid 1024 = 8 xcd * 8 slot * 16 qq; 4 waves/block, all of head bh = slot<<3|xcd.
// Waves w0/w1 share pair (gp=qq, gp'=63-qq); w2/w3 share (qq+16, 47-qq).
// Wave (pair, sub): seg1 = first-half tiles [0,h(u1)) of u1, seg2 = second-half
// [h(u2), n(u2)) of u2, where (u1,u2) = sub? (gp',gp) : (gp,gp'). Every wave runs
// 16-18 tiles -> perfect balance at 4 waves/SIMD (VGPR ~108). After seg1 each wave
// ships its partial (bf16x2-packed, 20 u32/lane) to ship[w]; one barrier; after seg2
// it combines with partner's (w^1) shipped partial and stores unit u2 (u2's second
// half contains the diagonal, so the mask ran in the right wave).
__global__ __launch_bounds__(256) void attn_fwd(const uint16_t* __restrict__ Q,
                                                const uint16_t* __restrict__ K,
                                                const uint16_t* __restrict__ Vt,
                                                uint16_t* __restrict__ Aout) {
  const int bid = blockIdx.x;
  const int xcd = bid & 7;
  const int slot = (bid >> 3) & 7;
  const int qq = bid >> 6;  // 0..15
  const int bh = (slot << 3) | xcd;

  const int w = threadIdx.x >> 6;
  const int lane = threadIdx.x & 63;
  const int l15 = lane & 15, lg = lane >> 4;

  const int gp = (w < 2) ? qq : (qq + 16);  // 0..31
  const int gq = 63 - gp;
  const int sub = w & 1;
  const int u1 = sub ? gq : gp;  // seg1: first half of u1
  const int u2 = sub ? gp : gq;  // seg2: second half of u2 (owns diagonal -> finalizes u2)

  const uint16_t* Qh = Q + (size_t)bh * (NS * 64);
  const uint16_t* Kh = K + (size_t)bh * (NS * 64);
  const uint16_t* Vh = Vt + (size_t)bh * (64 * NS);
  const int b = bh >> 4, h = bh & 15;

  __shared__ __align__(16) uint16_t plds[4][2][16][68];  // per-wave P buffers (17408 B)
  __shared__ uint32_t ship[4][20][64];                   // partial-sum exchange (20480 B)

  const int n1 = (u1 >> 1) + 1, h1 = n1 >> 1;
  const int n2 = (u2 >> 1) + 1, h2 = n2 >> 1;

  f32x4 oA[4], oB[4];
  f32x4 rsA = f32x4{0.f, 0.f, 0.f, 0.f};
  f32x4 rsB = f32x4{0.f, 0.f, 0.f, 0.f};
#pragma unroll
  for (int i = 0; i < 4; i++) {
    oA[i] = f32x4{0.f, 0.f, 0.f, 0.f};
    oB[i] = f32x4{0.f, 0.f, 0.f, 0.f};
  }

  // ---- segment 1: tiles [0, h1) of unit u1 (never reaches the diagonal) ----
  attn_seg(Qh, Kh, Vh, u1, 0, h1, l15, lg, plds[w], oA, oB, rsA, rsB);

  // ship seg1 partial to slot w (bf16x2-packed, conflict-free: bank = lane&31)
#pragma unroll
  for (int df = 0; df < 4; ++df) {
    ship[w][2 * df][lane]     = pk2(oA[df][0], oA[df][1]);
    ship[w][2 * df + 1][lane] = pk2(oA[df][2], oA[df][3]);
    ship[w][8 + 2 * df][lane]     = pk2(oB[df][0], oB[df][1]);
    ship[w][8 + 2 * df + 1][lane] = pk2(oB[df][2], oB[df][3]);
  }
  ship[w][16][lane] = pk2(rsA[0], rsA[1]);
  ship[w][17][lane] = pk2(rsA[2], rsA[3]);
  ship[w][18][lane] = pk2(rsB[0], rsB[1]);
  ship[w][19][lane] = pk2(rsB[2], rsB[3]);
  __syncthreads();

  // ---- segment 2: tiles [h2, n2) of unit u2 (fresh accumulators) ----
#pragma unroll
  for (int i = 0; i < 4; i++) {
    oA[i] = f32x4{0.f, 0.f, 0.f, 0.f};
    oB[i] = f32x4{0.f, 0.f, 0.f, 0.f};
  }
  rsA = f32x4{0.f, 0.f, 0.f, 0.f};
  rsB = f32x4{0.f, 0.f, 0.f, 0.f};
  attn_seg(Qh, Kh, Vh, u2, h2, n2, l15, lg, plds[w], oA, oB, rsA, rsB);

  // ---- combine with partner's seg1 partial (same unit u2) and store ----
  const int pw_ = w ^ 1;
#pragma unroll
  for (int df = 0; df < 4; ++df) {
    const uint32_t a0 = ship[pw_][2 * df][lane], a1 = ship[pw_][2 * df + 1][lane];
    oA[df][0] += unlo(a0); oA[df][1] += unhi(a0);
    oA[df][2] += unlo(a1); oA[df][3] += unhi(a1);
    const uint32_t b0 = ship[pw_][8 + 2 * df][lane], b1 = ship[pw_][8 + 2 * df + 1][lane];
    oB[df][0] += unlo(b0); oB[df][1] += unhi(b0);
    oB[df][2] += unlo(b1); oB[df][3] += unhi(b1);
  }
  {
    const uint32_t r0 = ship[pw_][16][lane], r1 = ship[pw_][17][lane];
    rsA[0] += unlo(r0); rsA[1] += unhi(r0); rsA[2] += unlo(r1); rsA[3] += unhi(r1);
    const uint32_t r2 = ship[pw_][18][lane], r3 = ship[pw_][19][lane];
    rsB[0] += unlo(r2); rsB[1] += unhi(r2); rsB[2] += unlo(r3); rsB[3] += unhi(r3);
  }

  const int qbA = u2 * 32;
  const int qbB = qbA + 16;
#pragma unroll
  for (int df = 0; df < 4; ++df) {
#pragma unroll
    for (int i = 0; i < 4; i++) {
      const int qA = qbA + lg * 4 + i;
      const int qB = qbB + lg * 4 + i;
      Aout[((size_t)(b * NS + qA)) * 1024 + h * 64 + df * 16 + l15] = f2bf(oA[df][i] / rsA[i]);
      Aout[((size_t)(b * NS + qB)) * 1024 + h * 64 + df * 16 + l15] = f2bf(oB[df][i] / rsB[i]);
    }
  }
}

extern "C" void kernel_launch(void* const* d_in, const int* in_sizes, int n_in,
                              void* d_out, int out_size, void* d_ws, size_t ws_size,
                              hipStream_t stream) {
  const float* x = (const float*)d_in[0];
  const float* Wq = (const float*)d_in[1];
  const float* Wk = (const float*)d_in[2];
  const float* Wv = (const float*)d_in[3];
  const float* Wo = (const float*)d_in[4];
  float* out = (float*)d_out;

  char* ws = (char*)d_ws;
  uint16_t* xb = (uint16_t*)(ws);                        // 16 MB  (reused as attn buffer)
  uint16_t* Wt3 = (uint16_t*)(ws + (16u << 20));         // 6 MB   [3][1024][1024] (n-major)
  uint16_t* Wot = (uint16_t*)(ws + (22u << 20));         // 2 MB
  uint16_t* Qb = (uint16_t*)(ws + (24u << 20));          // 16 MB  [BH][S][64]
  uint16_t* Kb = (uint16_t*)(ws + (40u << 20));          // 16 MB  [BH][S][64]
  uint16_t* Vt = (uint16_t*)(ws + (56u << 20));          // 16 MB  [BH][64][S]
  uint16_t* attn = xb;                                   // total 72 MB

  cvt_bf16_kernel<<<8192, 256, 0, stream>>>(x, xb, (NB * NS * ND) / 4);
  dim3 tb(32, 8);
  transpose_cvt<<<dim3(32, 32), tb, 0, stream>>>(Wq, Wt3);
  transpose_cvt<<<dim3(32, 32), tb, 0, stream>>>(Wk, Wt3 + (1u << 20));
  transpose_cvt<<<dim3(32, 32), tb, 0, stream>>>(Wv, Wt3 + (2u << 20));
  transpose_cvt<<<dim3(32, 32), tb, 0, stream>>>(Wo, Wot);

  gemm_bt<0><<<dim3(24, 64), 256, 0, stream>>>(xb, Wt3, Qb, Kb, Vt, nullptr);
  attn_fwd<<<1024, 256, 0, stream>>>(Qb, Kb, Vt, attn);
  gemm_bt<1><<<dim3(8, 64), 256, 0, stream>>>(attn, Wot, nullptr, nullptr, nullptr, out);
}

// Round 15
// 261.730 us; speedup vs baseline: 1.1363x; 1.1363x over previous
//
#include <hip/hip_runtime.h>
#include <stdint.h>

// Shapes (fixed): B=4, S=2048, D=1024, H=16, DH=64
#define NB 4
#define NS 2048
#define ND 1024
#define NH 16
#define NDH 64

typedef __attribute__((ext_vector_type(8))) short bf16x8;
typedef __attribute__((ext_vector_type(4))) float f32x4;
typedef __attribute__((ext_vector_type(2))) unsigned int u32x2;

#define MFMA16(a, b, c) __builtin_amdgcn_mfma_f32_16x16x32_bf16((a), (b), (c), 0, 0, 0)

__device__ __forceinline__ uint16_t f2bf(float f) {
  uint32_t u = __builtin_bit_cast(uint32_t, f);
  return (uint16_t)((u + 0x7FFFu + ((u >> 16) & 1u)) >> 16);
}

// truncating bf16x2 pack (for P values; downward bias cancels in o/rs ratio)
__device__ __forceinline__ uint32_t pk2(float lo, float hi) {
  return (__builtin_bit_cast(uint32_t, hi) & 0xFFFF0000u) |
         (__builtin_bit_cast(uint32_t, lo) >> 16);
}

__device__ __forceinline__ void gload_lds16(const void* g, void* l) {
  __builtin_amdgcn_global_load_lds(
      (const __attribute__((address_space(1))) uint32_t*)(uintptr_t)g,
      (__attribute__((address_space(3))) uint32_t*)(uintptr_t)l, 16, 0, 0);
}

// ---------------- fp32 -> bf16 convert (x) ----------------
__global__ __launch_bounds__(256) void cvt_bf16_kernel(const float* __restrict__ src,
                                                       uint16_t* __restrict__ dst, int n4) {
  int i = blockIdx.x * 256 + threadIdx.x;
  if (i >= n4) return;
  const float4 f = *(const float4*)(src + (size_t)i * 4);
  union { uint16_t u[4]; uint64_t q; } o;
  o.u[0] = f2bf(f.x); o.u[1] = f2bf(f.y); o.u[2] = f2bf(f.z); o.u[3] = f2bf(f.w);
  *(uint64_t*)(dst + (size_t)i * 4) = o.q;
}

// ---------------- transpose + convert: W[1024][1024] f32 -> Wt[n][k] bf16 ----------------
__global__ __launch_bounds__(256) void transpose_cvt(const float* __restrict__ W,
                                                     uint16_t* __restrict__ Wt) {
  __shared__ uint16_t tile[32][33];
  const int bx = blockIdx.x * 32;  // n
  const int by = blockIdx.y * 32;  // k
  const int tx = threadIdx.x;      // 0..31
  const int ty = threadIdx.y;      // 0..7
#pragma unroll
  for (int j = 0; j < 4; j++)
    tile[ty + j * 8][tx] = f2bf(W[(size_t)(by + ty + j * 8) * 1024 + bx + tx]);
  __syncthreads();
#pragma unroll
  for (int j = 0; j < 4; j++)
    Wt[(size_t)(bx + ty + j * 8) * 1024 + by + tx] = tile[tx][ty + j * 8];
}

// ---------------- GEMM: C[M][c] = A[M][K=1024] * Wt[c][K=1024]^T ----------------
// MODE 0: QKV projection, N=3072, scatter to Q [BH][S][64], K [BH][S][64], Vt [BH][64][S] (bf16)
// MODE 1: out projection, N=1024, write fp32 C row-major
template <int MODE>
__global__ __launch_bounds__(256) void gemm_bt(const uint16_t* __restrict__ A,
                                               const uint16_t* __restrict__ Bt,
                                               uint16_t* __restrict__ O0,
                                               uint16_t* __restrict__ O1,
                                               uint16_t* __restrict__ O2,
                                               float* __restrict__ OF) {
  __shared__ uint16_t lds[2][128 * 32];  // [0]=A tile [128][32], [1]=B tile [128][32]
  const int tid = threadIdx.x;
  const int lane = tid & 63;
  const int wave = tid >> 6;
  const int wr = wave >> 1, wc = wave & 1;
  const int l15 = lane & 15, lg = lane >> 4;
  const int row0 = blockIdx.y * 128;
  const int col0 = blockIdx.x * 128;

  f32x4 acc[4][4];
#pragma unroll
  for (int i = 0; i < 4; i++)
#pragma unroll
    for (int j = 0; j < 4; j++) acc[i][j] = f32x4{0.f, 0.f, 0.f, 0.f};

  const int srow = tid >> 2;          // 0..63
  const int scb = (tid & 3) * 16;     // byte offset within 64B row
  const char* Ab = (const char*)A;
  const char* Bb = (const char*)Bt;
  char* ldsA = (char*)&lds[0][0];
  char* ldsB = (char*)&lds[1][0];
  const int wbase = wave * 1024;      // wave-uniform LDS offset (HW adds lane*16)

  for (int kt = 0; kt < 1024; kt += 32) {
#pragma unroll
    for (int j = 0; j < 2; ++j) {
      const int r = j * 64 + srow;
      gload_lds16(Ab + ((size_t)(row0 + r) * 1024 + kt) * 2 + scb, ldsA + j * 4096 + wbase);
      gload_lds16(Bb + ((size_t)(col0 + r) * 1024 + kt) * 2 + scb, ldsB + j * 4096 + wbase);
    }
    __syncthreads();
    bf16x8 bfr[4];
#pragma unroll
    for (int ni = 0; ni < 4; ni++)
      bfr[ni] = *(const bf16x8*)&lds[1][(wc * 64 + ni * 16 + l15) * 32 + lg * 8];
#pragma unroll
    for (int mi = 0; mi < 4; mi++) {
      const bf16x8 afr = *(const bf16x8*)&lds[0][(wr * 64 + mi * 16 + l15) * 32 + lg * 8];
#pragma unroll
      for (int ni = 0; ni < 4; ni++) acc[mi][ni] = MFMA16(afr, bfr[ni], acc[mi][ni]);
    }
    __syncthreads();
  }

  // Epilogue. C/D layout: col = lane&15, row = (lane>>4)*4 + i  [m89-verified]
#pragma unroll
  for (int mi = 0; mi < 4; mi++) {
#pragma unroll
    for (int ni = 0; ni < 4; ni++) {
      const int c = col0 + wc * 64 + ni * 16 + l15;
      const int rbase = row0 + wr * 64 + mi * 16 + lg * 4;
#pragma unroll
      for (int i = 0; i < 4; i++) {
        const int r = rbase + i;
        const float v = acc[mi][ni][i];
        if (MODE == 0) {
          const int which = c >> 10, cc = c & 1023;
          const int h = cc >> 6, dh = cc & 63;
          const int b = r >> 11, s = r & 2047;
          const size_t hb = (size_t)(b * NH + h);
          if (which == 0)
            O0[(hb * NS + s) * 64 + dh] = f2bf(v * 0.18033688011112042f);  // (1/8)*log2(e)
          else if (which == 1)
            O1[(hb * NS + s) * 64 + dh] = f2bf(v);
          else
            O2[(hb * 64 + dh) * NS + s] = f2bf(v);
        } else {
          OF[(size_t)r * 1024 + c] = v;
        }
      }
    }
  }
}

// ---- one 32-row attention unit (round-10 structure, tr-read P path) ----
// Rows [32gp, 32gp+32) of head bh as dual 16-row chains A/B (same tmax, unconditional ->
// compiler interleaves, ILP-2). No-max softmax (logits ~N(0,1), |s*log2e| << 127):
// P=exp2(s), masked -> 0; denominator via ones-MFMA.
// P path: store P k-major pX[k=64][q=16] (QK C-layout lane holds 4 consecutive q at
// fixed k=nf*16+l15 -> ONE ds_write_b64 of truncating-packed bf16). Read A-frags with
// ds_read_b64_tr_b16: 16-lane group lg covers the 4x16 row-major subtile at
// base + lg*256 + l15*8 (per-lane chunk addr!), hw delivers column l15 -> lane gets
// P[q=l15][k=lg*8+j]; offsets {0,128,1024,1152} walk k in {+0,+4,+32,+36}.
__device__ __forceinline__ void attn_unit(const uint16_t* __restrict__ Qh,
                                          const uint16_t* __restrict__ Kh,
                                          const uint16_t* __restrict__ Vh,
                                          uint16_t* __restrict__ Aout,
                                          int b, int h, int gp, int l15, int lg,
                                          uint16_t (*pX)[64][16]) {
  const int qbA = gp * 32;
  const int qbB = qbA + 16;
  const int tmax = gp >> 1;          // same last tile for both chains
  const int nfdA = (2 * gp) & 3;     // 0 or 2
  const int nfdB = nfdA + 1;

  const bf16x8 qfA0 = *(const bf16x8*)&Qh[(size_t)(qbA + l15) * 64 + lg * 8];
  const bf16x8 qfA1 = *(const bf16x8*)&Qh[(size_t)(qbA + l15) * 64 + 32 + lg * 8];
  const bf16x8 qfB0 = *(const bf16x8*)&Qh[(size_t)(qbB + l15) * 64 + lg * 8];
  const bf16x8 qfB1 = *(const bf16x8*)&Qh[(size_t)(qbB + l15) * 64 + 32 + lg * 8];

  const short one_bf = (short)0x3F80;  // bf16 1.0
  const bf16x8 ones = {one_bf, one_bf, one_bf, one_bf, one_bf, one_bf, one_bf, one_bf};

  // tr-read per-lane addresses (chunk-gather: lane covers its own 8B of the 4x16 tile)
  const uint32_t baseA = (uint32_t)(uintptr_t)&pX[0][0][0] + (uint32_t)(lg * 256 + l15 * 8);
  const uint32_t baseB = baseA + 2048;  // pX[1] is 64*16*2 bytes after pX[0]

  f32x4 oA[4], oB[4];
  f32x4 rsA = f32x4{0.f, 0.f, 0.f, 0.f};
  f32x4 rsB = f32x4{0.f, 0.f, 0.f, 0.f};
#pragma unroll
  for (int i = 0; i < 4; i++) {
    oA[i] = f32x4{0.f, 0.f, 0.f, 0.f};
    oB[i] = f32x4{0.f, 0.f, 0.f, 0.f};
  }

  for (int t = 0; t <= tmax; ++t) {
    // prefetch V fragments for this tile (shared by both chains)
    bf16x8 vr[4][2];
#pragma unroll
    for (int df = 0; df < 4; ++df) {
      const uint16_t* vp = &Vh[(size_t)(df * 16 + l15) * NS + t * 64 + lg * 8];
      vr[df][0] = *(const bf16x8*)vp;
      vr[df][1] = *(const bf16x8*)(vp + 32);
    }
    const int nfmA = (t == tmax) ? nfdA : 3;
    const int nfmB = (t == tmax) ? nfdB : 3;
#pragma unroll
    for (int nf = 0; nf < 4; ++nf) {
      if (nf <= nfmB) {
        const uint16_t* kp = &Kh[(size_t)(t * 64 + nf * 16 + l15) * 64 + lg * 8];
        const bf16x8 k0 = *(const bf16x8*)kp;
        const bf16x8 k1 = *(const bf16x8*)(kp + 32);
        f32x4 a = f32x4{0.f, 0.f, 0.f, 0.f};
        a = MFMA16(qfB0, k0, a);
        a = MFMA16(qfB1, k1, a);
        if (t == tmax && nf == nfdB) {  // chain-B diagonal fragment: mask col > row
#pragma unroll
          for (int i = 0; i < 4; i++)
            if (l15 > lg * 4 + i) a[i] = -1e30f;
        }
        {
          const float e0 = exp2f(a[0]), e1 = exp2f(a[1]);
          const float e2 = exp2f(a[2]), e3 = exp2f(a[3]);
          *(uint64_t*)&pX[1][nf * 16 + l15][lg * 4] =
              ((uint64_t)pk2(e2, e3) << 32) | pk2(e0, e1);
        }
        if (nf <= nfmA) {
          f32x4 c = f32x4{0.f, 0.f, 0.f, 0.f};
          c = MFMA16(qfA0, k0, c);
          c = MFMA16(qfA1, k1, c);
          if (t == tmax && nf == nfdA) {
#pragma unroll
            for (int i = 0; i < 4; i++)
              if (l15 > lg * 4 + i) c[i] = -1e30f;
          }
          const float e0 = exp2f(c[0]), e1 = exp2f(c[1]);
          const float e2 = exp2f(c[2]), e3 = exp2f(c[3]);
          *(uint64_t*)&pX[0][nf * 16 + l15][lg * 4] =
              ((uint64_t)pk2(e2, e3) << 32) | pk2(e0, e1);
        } else {
          *(uint64_t*)&pX[0][nf * 16 + l15][lg * 4] = 0ull;
        }
      } else {
        *(uint64_t*)&pX[0][nf * 16 + l15][lg * 4] = 0ull;
        *(uint64_t*)&pX[1][nf * 16 + l15][lg * 4] = 0ull;
      }
    }
    // transpose-read P fragments (waitcnt inside; MFMA data-depends on outputs)
    u32x2 a0, a1, a2, a3, b0, b1, b2, b3;
    asm volatile(
        "ds_read_b64_tr_b16 %0, %8\n\t"
        "ds_read_b64_tr_b16 %1, %8 offset:128\n\t"
        "ds_read_b64_tr_b16 %2, %8 offset:1024\n\t"
        "ds_read_b64_tr_b16 %3, %8 offset:1152\n\t"
        "ds_read_b64_tr_b16 %4, %9\n\t"
        "ds_read_b64_tr_b16 %5, %9 offset:128\n\t"
        "ds_read_b64_tr_b16 %6, %9 offset:1024\n\t"
        "ds_read_b64_tr_b16 %7, %9 offset:1152\n\t"
        "s_waitcnt lgkmcnt(0)"
        : "=&v"(a0), "=&v"(a1), "=&v"(a2), "=&v"(a3),
          "=&v"(b0), "=&v"(b1), "=&v"(b2), "=&v"(b3)
        : "v"(baseA), "v"(baseB)
        : "memory");
    union { u32x2 u2[2]; bf16x8 v8; } uA0, uA1, uB0, uB1;
    uA0.u2[0] = a0; uA0.u2[1] = a1;  // k = lg*8 + 0..7
    uA1.u2[0] = a2; uA1.u2[1] = a3;  // k = 32 + lg*8 + 0..7
    uB0.u2[0] = b0; uB0.u2[1] = b1;
    uB1.u2[0] = b2; uB1.u2[1] = b3;
    const bf16x8 paA0 = uA0.v8, paA1 = uA1.v8;
    const bf16x8 paB0 = uB0.v8, paB1 = uB1.v8;
    rsA = MFMA16(paA0, ones, rsA);
    rsA = MFMA16(paA1, ones, rsA);
    rsB = MFMA16(paB0, ones, rsB);
    rsB = MFMA16(paB1, ones, rsB);
#pragma unroll
    for (int df = 0; df < 4; ++df) {
      oA[df] = MFMA16(paA0, vr[df][0], oA[df]);
      oA[df] = MFMA16(paA1, vr[df][1], oA[df]);
      oB[df] = MFMA16(paB0, vr[df][0], oB[df]);
      oB[df] = MFMA16(paB1, vr[df][1], oB[df]);
    }
  }

#pragma unroll
  for (int df = 0; df < 4; ++df) {
#pragma unroll
    for (int i = 0; i < 4; i++) {
      const int qA = qbA + lg * 4 + i;
      const int qB = qbB + lg * 4 + i;
      Aout[((size_t)(b * NS + qA)) * 1024 + h * 64 + df * 16 + l15] = f2bf(oA[df][i] / rsA[i]);
      Aout[((size_t)(b * NS + qB)) * 1024 + h * 64 + df * 16 + l15] = f2bf(oB[df][i] / rsB[i]);
    }
  }
}

// ---------------- causal flash attention (wave = two sequential balanced units) ----------------
// grid 512 blocks x 4 waves = 2048 waves. Block decode: xcd = bid&7, sp = (bid>>3)&3,
// gblk = bid>>5; wave w -> g = gblk*4 + w (0..63).
// Wave runs unit (bh = (2sp)<<3|xcd, gp = g) then unit (bh = (2sp+1)<<3|xcd, gp = 63-g):
// total iterations = 33..34 for EVERY wave -> no stragglers; both heads on one XCD.
__global__ __launch_bounds__(256) void attn_fwd(const uint16_t* __restrict__ Q,
                                                const uint16_t* __restrict__ K,
                                                const uint16_t* __restrict__ Vt,
                                                uint16_t* __restrict__ Aout) {
  const int bid = blockIdx.x;
  const int xcd = bid & 7;
  const int sp = (bid >> 3) & 3;
  const int gblk = bid >> 5;  // 0..15

  const int w = threadIdx.x >> 6;
  const int lane = threadIdx.x & 63;
  const int l15 = lane & 15, lg = lane >> 4;
  const int g = gblk * 4 + w;  // 0..63

  // per-wave k-major P buffers: [chain][k=64][q=16] u16 (4 KB/wave)
  __shared__ __align__(16) uint16_t plds[4][2][64][16];

  for (int seg = 0; seg < 2; ++seg) {
    const int slot = sp * 2 + seg;
    const int bh = (slot << 3) | xcd;
    const int gp = seg ? (63 - g) : g;
    const uint16_t* Qh = Q + (size_t)bh * (NS * 64);
    const uint16_t* Kh = K + (size_t)bh * (NS * 64);
    const uint16_t* Vh = Vt + (size_t)bh * (64 * NS);
    attn_unit(Qh, Kh, Vh, Aout, bh >> 4, bh & 15, gp, l15, lg, plds[w]);
  }
}

extern "C" void kernel_launch(void* const* d_in, const int* in_sizes, int n_in,
                              void* d_out, int out_size, void* d_ws, size_t ws_size,
                              hipStream_t stream) {
  const float* x = (const float*)d_in[0];
  const float* Wq = (const float*)d_in[1];
  const float* Wk = (const float*)d_in[2];
  const float* Wv = (const float*)d_in[3];
  const float* Wo = (const float*)d_in[4];
  float* out = (float*)d_out;

  char* ws = (char*)d_ws;
  uint16_t* xb = (uint16_t*)(ws);                        // 16 MB  (reused as attn buffer)
  uint16_t* Wt3 = (uint16_t*)(ws + (16u << 20));         // 6 MB   [3][1024][1024] (n-major)
  uint16_t* Wot = (uint16_t*)(ws + (22u << 20));         // 2 MB
  uint16_t* Qb = (uint16_t*)(ws + (24u << 20));          // 16 MB  [BH][S][64]
  uint16_t* Kb = (uint16_t*)(ws + (40u << 20));          // 16 MB  [BH][S][64]
  uint16_t* Vt = (uint16_t*)(ws + (56u << 20));          // 16 MB  [BH][64][S]
  uint16_t* attn = xb;                                   // total 72 MB

  cvt_bf16_kernel<<<8192, 256, 0, stream>>>(x, xb, (NB * NS * ND) / 4);
  dim3 tb(32, 8);
  transpose_cvt<<<dim3(32, 32), tb, 0, stream>>>(Wq, Wt3);
  transpose_cvt<<<dim3(32, 32), tb, 0, stream>>>(Wk, Wt3 + (1u << 20));
  transpose_cvt<<<dim3(32, 32), tb, 0, stream>>>(Wv, Wt3 + (2u << 20));
  transpose_cvt<<<dim3(32, 32), tb, 0, stream>>>(Wo, Wot);

  gemm_bt<0><<<dim3(24, 64), 256, 0, stream>>>(xb, Wt3, Qb, Kb, Vt, nullptr);
  attn_fwd<<<512, 256, 0, stream>>>(Qb, Kb, Vt, attn);
  gemm_bt<1><<<dim3(8, 64), 256, 0, stream>>>(attn, Wot, nullptr, nullptr, nullptr, out);
}

// Round 16
// 246.573 us; speedup vs baseline: 1.2062x; 1.0615x over previous
//
#include <hip/hip_runtime.h>
#include <stdint.h>

// Shapes (fixed): B=4, S=2048, D=1024, H=16, DH=64
#define NB 4
#define NS 2048
#define ND 1024
#define NH 16
#define NDH 64

typedef __attribute__((ext_vector_type(8))) short bf16x8;
typedef __attribute__((ext_vector_type(4))) float f32x4;
typedef __attribute__((ext_vector_type(2))) unsigned int u32x2;

#define MFMA16(a, b, c) __builtin_amdgcn_mfma_f32_16x16x32_bf16((a), (b), (c), 0, 0, 0)

__device__ __forceinline__ uint16_t f2bf(float f) {
  uint32_t u = __builtin_bit_cast(uint32_t, f);
  return (uint16_t)((u + 0x7FFFu + ((u >> 16) & 1u)) >> 16);
}

// truncating bf16x2 pack (for P values; downward bias cancels in o/rs ratio)
__device__ __forceinline__ uint32_t pk2(float lo, float hi) {
  return (__builtin_bit_cast(uint32_t, hi) & 0xFFFF0000u) |
         (__builtin_bit_cast(uint32_t, lo) >> 16);
}

__device__ __forceinline__ void gload_lds16(const void* g, void* l) {
  __builtin_amdgcn_global_load_lds(
      (const __attribute__((address_space(1))) uint32_t*)(uintptr_t)g,
      (__attribute__((address_space(3))) uint32_t*)(uintptr_t)l, 16, 0, 0);
}

// ---------------- fp32 -> bf16 convert (x) ----------------
__global__ __launch_bounds__(256) void cvt_bf16_kernel(const float* __restrict__ src,
                                                       uint16_t* __restrict__ dst, int n4) {
  int i = blockIdx.x * 256 + threadIdx.x;
  if (i >= n4) return;
  const float4 f = *(const float4*)(src + (size_t)i * 4);
  union { uint16_t u[4]; uint64_t q; } o;
  o.u[0] = f2bf(f.x); o.u[1] = f2bf(f.y); o.u[2] = f2bf(f.z); o.u[3] = f2bf(f.w);
  *(uint64_t*)(dst + (size_t)i * 4) = o.q;
}

// ---------------- transpose + convert: W[1024][1024] f32 -> Wt[n][k] bf16 ----------------
__global__ __launch_bounds__(256) void transpose_cvt(const float* __restrict__ W,
                                                     uint16_t* __restrict__ Wt) {
  __shared__ uint16_t tile[32][33];
  const int bx = blockIdx.x * 32;  // n
  const int by = blockIdx.y * 32;  // k
  const int tx = threadIdx.x;      // 0..31
  const int ty = threadIdx.y;      // 0..7
#pragma unroll
  for (int j = 0; j < 4; j++)
    tile[ty + j * 8][tx] = f2bf(W[(size_t)(by + ty + j * 8) * 1024 + bx + tx]);
  __syncthreads();
#pragma unroll
  for (int j = 0; j < 4; j++)
    Wt[(size_t)(bx + ty + j * 8) * 1024 + by + tx] = tile[tx][ty + j * 8];
}

// ---------------- GEMM: C[M][c] = A[M][K=1024] * Wt[c][K=1024]^T ----------------
// MODE 0: QKV projection, NBX=24 (N=3072), scatter to Q/K [BH][S][64], Vt [BH][64][S]
// MODE 1: out projection, NBX=8 (N=1024), fp32 C row-major
// Grid is 1-D (NBX*64 blocks, %32==0). Decode: per-XCD contiguous chunk (T1), then
// 8y x 4x supertiles: one super-row per XCD visit -> the 8 A-panels (2MB) stay
// L2-resident across all NBX col-blocks; B cycles through L2/L3. Pure bijective remap.
template <int MODE, int NBX>
__global__ __launch_bounds__(256) void gemm_bt(const uint16_t* __restrict__ A,
                                               const uint16_t* __restrict__ Bt,
                                               uint16_t* __restrict__ O0,
                                               uint16_t* __restrict__ O1,
                                               uint16_t* __restrict__ O2,
                                               float* __restrict__ OF) {
  __shared__ uint16_t lds[2][128 * 32];  // [0]=A tile [128][32], [1]=B tile [128][32]
  const int tid = threadIdx.x;
  const int lane = tid & 63;
  const int wave = tid >> 6;
  const int wr = wave >> 1, wc = wave & 1;
  const int l15 = lane & 15, lg = lane >> 4;

  // XCD-chunked supertile decode
  const int nwg = NBX * 64;
  const int wg = ((int)blockIdx.x & 7) * (nwg >> 3) + ((int)blockIdx.x >> 3);
  const int st = wg >> 5, in32 = wg & 31;
  const int sy = in32 >> 2, sx = in32 & 3;
  const int stx = st % (NBX / 4), sty = st / (NBX / 4);
  const int row0 = (sty * 8 + sy) * 128;
  const int col0 = (stx * 4 + sx) * 128;

  f32x4 acc[4][4];
#pragma unroll
  for (int i = 0; i < 4; i++)
#pragma unroll
    for (int j = 0; j < 4; j++) acc[i][j] = f32x4{0.f, 0.f, 0.f, 0.f};

  const int srow = tid >> 2;          // 0..63
  const int scb = (tid & 3) * 16;     // byte offset within 64B row
  const char* Ab = (const char*)A;
  const char* Bb = (const char*)Bt;
  char* ldsA = (char*)&lds[0][0];
  char* ldsB = (char*)&lds[1][0];
  const int wbase = wave * 1024;      // wave-uniform LDS offset (HW adds lane*16)

  for (int kt = 0; kt < 1024; kt += 32) {
#pragma unroll
    for (int j = 0; j < 2; ++j) {
      const int r = j * 64 + srow;
      gload_lds16(Ab + ((size_t)(row0 + r) * 1024 + kt) * 2 + scb, ldsA + j * 4096 + wbase);
      gload_lds16(Bb + ((size_t)(col0 + r) * 1024 + kt) * 2 + scb, ldsB + j * 4096 + wbase);
    }
    __syncthreads();
    bf16x8 bfr[4];
#pragma unroll
    for (int ni = 0; ni < 4; ni++)
      bfr[ni] = *(const bf16x8*)&lds[1][(wc * 64 + ni * 16 + l15) * 32 + lg * 8];
#pragma unroll
    for (int mi = 0; mi < 4; mi++) {
      const bf16x8 afr = *(const bf16x8*)&lds[0][(wr * 64 + mi * 16 + l15) * 32 + lg * 8];
#pragma unroll
      for (int ni = 0; ni < 4; ni++) acc[mi][ni] = MFMA16(afr, bfr[ni], acc[mi][ni]);
    }
    __syncthreads();
  }

  // Epilogue. C/D layout: col = lane&15, row = (lane>>4)*4 + i  [m89-verified]
#pragma unroll
  for (int mi = 0; mi < 4; mi++) {
#pragma unroll
    for (int ni = 0; ni < 4; ni++) {
      const int c = col0 + wc * 64 + ni * 16 + l15;
      const int rbase = row0 + wr * 64 + mi * 16 + lg * 4;
#pragma unroll
      for (int i = 0; i < 4; i++) {
        const int r = rbase + i;
        const float v = acc[mi][ni][i];
        if (MODE == 0) {
          const int which = c >> 10, cc = c & 1023;
          const int h = cc >> 6, dh = cc & 63;
          const int b = r >> 11, s = r & 2047;
          const size_t hb = (size_t)(b * NH + h);
          if (which == 0)
            O0[(hb * NS + s) * 64 + dh] = f2bf(v * 0.18033688011112042f);  // (1/8)*log2(e)
          else if (which == 1)
            O1[(hb * NS + s) * 64 + dh] = f2bf(v);
          else
            O2[(hb * 64 + dh) * NS + s] = f2bf(v);
        } else {
          OF[(size_t)r * 1024 + c] = v;
        }
      }
    }
  }
}

// ---- one 32-row attention unit (round-10 structure, swizzled tr-read P path) ----
// Rows [32gp, 32gp+32) of head bh as dual 16-row chains A/B (same tmax, unconditional ->
// compiler interleaves, ILP-2). No-max softmax (logits ~N(0,1), |s*log2e| << 127):
// P=exp2(s), masked -> 0; denominator via ones-MFMA.
// P path: k-major pX[k=64][q=16], q-chunk ROTATED by (k>>2)&3 within each 32B row
// (chunk' = (chunk + (k>>2)) & 3). This spreads writer lanes (fixed lg,nf; k=nf*16+l15)
// and tr-reader lg-groups over 16 distinct bank-pairs -> 2 lanes/bank per 32-lane phase
// (free per m136), vs 4-way unswizzled (round-15: 7.57M conflicts).
// tr-reads use per-lane swizzled addresses (honored by HW: m162 uniform-addr result
// proves no internal lane offset): lane fetches logical chunk (r=l15>>2, c=l15&3) of the
// 4x16 subtile at rows k0..k0+3 from its rotated location; gathered lane order stays
// row-major so the hardware transpose delivers P[q=l15][k=lg*8+j] as before.
__device__ __forceinline__ void attn_unit(const uint16_t* __restrict__ Qh,
                                          const uint16_t* __restrict__ Kh,
                                          const uint16_t* __restrict__ Vh,
                                          uint16_t* __restrict__ Aout,
                                          int b, int h, int gp, int l15, int lg,
                                          uint16_t (*pX)[64][16]) {
  const int qbA = gp * 32;
  const int qbB = qbA + 16;
  const int tmax = gp >> 1;          // same last tile for both chains
  const int nfdA = (2 * gp) & 3;     // 0 or 2
  const int nfdB = nfdA + 1;

  const bf16x8 qfA0 = *(const bf16x8*)&Qh[(size_t)(qbA + l15) * 64 + lg * 8];
  const bf16x8 qfA1 = *(const bf16x8*)&Qh[(size_t)(qbA + l15) * 64 + 32 + lg * 8];
  const bf16x8 qfB0 = *(const bf16x8*)&Qh[(size_t)(qbB + l15) * 64 + lg * 8];
  const bf16x8 qfB1 = *(const bf16x8*)&Qh[(size_t)(qbB + l15) * 64 + 32 + lg * 8];

  const short one_bf = (short)0x3F80;  // bf16 1.0
  const bf16x8 ones = {one_bf, one_bf, one_bf, one_bf, one_bf, one_bf, one_bf, one_bf};

  // write col (u16 units): chunk' = (lg + (k>>2))&3 with (k>>2)&3 == l15>>2 (k=nf*16+l15)
  const int wcol = ((lg + (l15 >> 2)) & 3) * 4;

  // tr-read per-lane swizzled addresses. Logical chunk (r=l15>>2, c=l15&3);
  // rot(k0) = (k0>>2)&3: k0=lg*8 -> rot=2lg&3 (same for +32); k0=lg*8+4 -> rot+1.
  const int rr = l15 >> 2, cc0 = l15 & 3;
  const int rot = (2 * lg) & 3;
  const uint32_t pb = (uint32_t)(uintptr_t)&pX[0][0][0];
  const uint32_t addr0 = pb + (uint32_t)(lg * 256 + rr * 32 + (((cc0 + rot) & 3) * 8));
  const uint32_t addr1 = pb + (uint32_t)(lg * 256 + 128 + rr * 32 + (((cc0 + rot + 1) & 3) * 8));

  f32x4 oA[4], oB[4];
  f32x4 rsA = f32x4{0.f, 0.f, 0.f, 0.f};
  f32x4 rsB = f32x4{0.f, 0.f, 0.f, 0.f};
#pragma unroll
  for (int i = 0; i < 4; i++) {
    oA[i] = f32x4{0.f, 0.f, 0.f, 0.f};
    oB[i] = f32x4{0.f, 0.f, 0.f, 0.f};
  }

  for (int t = 0; t <= tmax; ++t) {
    // prefetch V fragments for this tile (shared by both chains)
    bf16x8 vr[4][2];
#pragma unroll
    for (int df = 0; df < 4; ++df) {
      const uint16_t* vp = &Vh[(size_t)(df * 16 + l15) * NS + t * 64 + lg * 8];
      vr[df][0] = *(const bf16x8*)vp;
      vr[df][1] = *(const bf16x8*)(vp + 32);
    }
    const int nfmA = (t == tmax) ? nfdA : 3;
    const int nfmB = (t == tmax) ? nfdB : 3;
#pragma unroll
    for (int nf = 0; nf < 4; ++nf) {
      if (nf <= nfmB) {
        const uint16_t* kp = &Kh[(size_t)(t * 64 + nf * 16 + l15) * 64 + lg * 8];
        const bf16x8 k0 = *(const bf16x8*)kp;
        const bf16x8 k1 = *(const bf16x8*)(kp + 32);
        f32x4 a = f32x4{0.f, 0.f, 0.f, 0.f};
        a = MFMA16(qfB0, k0, a);
        a = MFMA16(qfB1, k1, a);
        if (t == tmax && nf == nfdB) {  // chain-B diagonal fragment: mask col > row
#pragma unroll
          for (int i = 0; i < 4; i++)
            if (l15 > lg * 4 + i) a[i] = -1e30f;
        }
        {
          const float e0 = exp2f(a[0]), e1 = exp2f(a[1]);
          const float e2 = exp2f(a[2]), e3 = exp2f(a[3]);
          *(uint64_t*)&pX[1][nf * 16 + l15][wcol] =
              ((uint64_t)pk2(e2, e3) << 32) | pk2(e0, e1);
        }
        if (nf <= nfmA) {
          f32x4 c = f32x4{0.f, 0.f, 0.f, 0.f};
          c = MFMA16(qfA0, k0, c);
          c = MFMA16(qfA1, k1, c);
          if (t == tmax && nf == nfdA) {
#pragma unroll
            for (int i = 0; i < 4; i++)
              if (l15 > lg * 4 + i) c[i] = -1e30f;
          }
          const float e0 = exp2f(c[0]), e1 = exp2f(c[1]);
          const float e2 = exp2f(c[2]), e3 = exp2f(c[3]);
          *(uint64_t*)&pX[0][nf * 16 + l15][wcol] =
              ((uint64_t)pk2(e2, e3) << 32) | pk2(e0, e1);
        } else {
          *(uint64_t*)&pX[0][nf * 16 + l15][wcol] = 0ull;
        }
      } else {
        *(uint64_t*)&pX[0][nf * 16 + l15][wcol] = 0ull;
        *(uint64_t*)&pX[1][nf * 16 + l15][wcol] = 0ull;
      }
    }
    // transpose-read P fragments (waitcnt inside; MFMA data-depends on outputs).
    // addr0: k0 = lg*8 (+1024 -> +32 rows); addr1: k0 = lg*8+4. Chain B at +2048.
    u32x2 a0, a1, a2, a3, b0, b1, b2, b3;
    asm volatile(
        "ds_read_b64_tr_b16 %0, %8\n\t"
        "ds_read_b64_tr_b16 %1, %9\n\t"
        "ds_read_b64_tr_b16 %2, %8 offset:1024\n\t"
        "ds_read_b64_tr_b16 %3, %9 offset:1024\n\t"
        "ds_read_b64_tr_b16 %4, %8 offset:2048\n\t"
        "ds_read_b64_tr_b16 %5, %9 offset:2048\n\t"
        "ds_read_b64_tr_b16 %6, %8 offset:3072\n\t"
        "ds_read_b64_tr_b16 %7, %9 offset:3072\n\t"
        "s_waitcnt lgkmcnt(0)"
        : "=&v"(a0), "=&v"(a1), "=&v"(a2), "=&v"(a3),
          "=&v"(b0), "=&v"(b1), "=&v"(b2), "=&v"(b3)
        : "v"(addr0), "v"(addr1)
        : "memory");
    union { u32x2 u2[2]; bf16x8 v8; } uA0, uA1, uB0, uB1;
    uA0.u2[0] = a0; uA0.u2[1] = a1;  // k = lg*8 + 0..7
    uA1.u2[0] = a2; uA1.u2[1] = a3;  // k = 32 + lg*8 + 0..7
    uB0.u2[0] = b0; uB0.u2[1] = b1;
    uB1.u2[0] = b2; uB1.u2[1] = b3;
    const bf16x8 paA0 = uA0.v8, paA1 = uA1.v8;
    const bf16x8 paB0 = uB0.v8, paB1 = uB1.v8;
    rsA = MFMA16(paA0, ones, rsA);
    rsA = MFMA16(paA1, ones, rsA);
    rsB = MFMA16(paB0, ones, rsB);
    rsB = MFMA16(paB1, ones, rsB);
#pragma unroll
    for (int df = 0; df < 4; ++df) {
      oA[df] = MFMA16(paA0, vr[df][0], oA[df]);
      oA[df] = MFMA16(paA1, vr[df][1], oA[df]);
      oB[df] = MFMA16(paB0, vr[df][0], oB[df]);
      oB[df] = MFMA16(paB1, vr[df][1], oB[df]);
    }
  }

#pragma unroll
  for (int df = 0; df < 4; ++df) {
#pragma unroll
    for (int i = 0; i < 4; i++) {
      const int qA = qbA + lg * 4 + i;
      const int qB = qbB + lg * 4 + i;
      Aout[((size_t)(b * NS + qA)) * 1024 + h * 64 + df * 16 + l15] = f2bf(oA[df][i] / rsA[i]);
      Aout[((size_t)(b * NS + qB)) * 1024 + h * 64 + df * 16 + l15] = f2bf(oB[df][i] / rsB[i]);
    }
  }
}

// ---------------- causal flash attention (wave = two sequential balanced units) ----------------
// grid 512 blocks x 4 waves = 2048 waves. Block decode: xcd = bid&7, sp = (bid>>3)&3,
// gblk = bid>>5; wave w -> g = gblk*4 + w (0..63).
// Wave runs unit (bh = (2sp)<<3|xcd, gp = g) then unit (bh = (2sp+1)<<3|xcd, gp = 63-g):
// total iterations = 33..34 for EVERY wave -> no stragglers; both heads on one XCD.
__global__ __launch_bounds__(256) void attn_fwd(const uint16_t* __restrict__ Q,
                                                const uint16_t* __restrict__ K,
                                                const uint16_t* __restrict__ Vt,
                                                uint16_t* __restrict__ Aout) {
  const int bid = blockIdx.x;
  const int xcd = bid & 7;
  const int sp = (bid >> 3) & 3;
  const int gblk = bid >> 5;  // 0..15

  const int w = threadIdx.x >> 6;
  const int lane = threadIdx.x & 63;
  const int l15 = lane & 15, lg = lane >> 4;
  const int g = gblk * 4 + w;  // 0..63

  // per-wave k-major P buffers: [chain][k=64][q=16] u16 (4 KB/wave)
  __shared__ __align__(16) uint16_t plds[4][2][64][16];

  for (int seg = 0; seg < 2; ++seg) {
    const int slot = sp * 2 + seg;
    const int bh = (slot << 3) | xcd;
    const int gp = seg ? (63 - g) : g;
    const uint16_t* Qh = Q + (size_t)bh * (NS * 64);
    const uint16_t* Kh = K + (size_t)bh * (NS * 64);
    const uint16_t* Vh = Vt + (size_t)bh * (64 * NS);
    attn_unit(Qh, Kh, Vh, Aout, bh >> 4, bh & 15, gp, l15, lg, plds[w]);
  }
}

extern "C" void kernel_launch(void* const* d_in, const int* in_sizes, int n_in,
                              void* d_out, int out_size, void* d_ws, size_t ws_size,
                              hipStream_t stream) {
  const float* x = (const float*)d_in[0];
  const float* Wq = (const float*)d_in[1];
  const float* Wk = (const float*)d_in[2];
  const float* Wv = (const float*)d_in[3];
  const float* Wo = (const float*)d_in[4];
  float* out = (float*)d_out;

  char* ws = (char*)d_ws;
  uint16_t* xb = (uint16_t*)(ws);                        // 16 MB  (reused as attn buffer)
  uint16_t* Wt3 = (uint16_t*)(ws + (16u << 20));         // 6 MB   [3][1024][1024] (n-major)
  uint16_t* Wot = (uint16_t*)(ws + (22u << 20));         // 2 MB
  uint16_t* Qb = (uint16_t*)(ws + (24u << 20));          // 16 MB  [BH][S][64]
  uint16_t* Kb = (uint16_t*)(ws + (40u << 20));          // 16 MB  [BH][S][64]
  uint16_t* Vt = (uint16_t*)(ws + (56u << 20));          // 16 MB  [BH][64][S]
  uint16_t* attn = xb;                                   // total 72 MB

  cvt_bf16_kernel<<<8192, 256, 0, stream>>>(x, xb, (NB * NS * ND) / 4);
  dim3 tb(32, 8);
  transpose_cvt<<<dim3(32, 32), tb, 0, stream>>>(Wq, Wt3);
  transpose_cvt<<<dim3(32, 32), tb, 0, stream>>>(Wk, Wt3 + (1u << 20));
  transpose_cvt<<<dim3(32, 32), tb, 0, stream>>>(Wv, Wt3 + (2u << 20));
  transpose_cvt<<<dim3(32, 32), tb, 0, stream>>>(Wo, Wot);

  gemm_bt<0, 24><<<1536, 256, 0, stream>>>(xb, Wt3, Qb, Kb, Vt, nullptr);
  attn_fwd<<<512, 256, 0, stream>>>(Qb, Kb, Vt, attn);
  gemm_bt<1, 8><<<512, 256, 0, stream>>>(attn, Wot, nullptr, nullptr, nullptr, out);
}

// Round 17
// 196.380 us; speedup vs baseline: 1.5145x; 1.2556x over previous
//
#include <hip/hip_runtime.h>
#include <stdint.h>

// Shapes (fixed): B=4, S=2048, D=1024, H=16, DH=64
#define NB 4
#define NS 2048
#define ND 1024
#define NH 16
#define NDH 64

typedef __attribute__((ext_vector_type(8))) short bf16x8;
typedef __attribute__((ext_vector_type(4))) float f32x4;
typedef __attribute__((ext_vector_type(2))) unsigned int u32x2;

#define MFMA16(a, b, c) __builtin_amdgcn_mfma_f32_16x16x32_bf16((a), (b), (c), 0, 0, 0)

__device__ __forceinline__ uint16_t f2bf(float f) {
  uint32_t u = __builtin_bit_cast(uint32_t, f);
  return (uint16_t)((u + 0x7FFFu + ((u >> 16) & 1u)) >> 16);
}

// truncating bf16x2 pack (for P values; downward bias cancels in o/rs ratio)
__device__ __forceinline__ uint32_t pk2(float lo, float hi) {
  return (__builtin_bit_cast(uint32_t, hi) & 0xFFFF0000u) |
         (__builtin_bit_cast(uint32_t, lo) >> 16);
}

__device__ __forceinline__ void gload_lds16(const void* g, void* l) {
  __builtin_amdgcn_global_load_lds(
      (const __attribute__((address_space(1))) uint32_t*)(uintptr_t)g,
      (__attribute__((address_space(3))) uint32_t*)(uintptr_t)l, 16, 0, 0);
}

// ---------------- fp32 -> bf16 convert (x) ----------------
__global__ __launch_bounds__(256) void cvt_bf16_kernel(const float* __restrict__ src,
                                                       uint16_t* __restrict__ dst, int n4) {
  int i = blockIdx.x * 256 + threadIdx.x;
  if (i >= n4) return;
  const float4 f = *(const float4*)(src + (size_t)i * 4);
  union { uint16_t u[4]; uint64_t q; } o;
  o.u[0] = f2bf(f.x); o.u[1] = f2bf(f.y); o.u[2] = f2bf(f.z); o.u[3] = f2bf(f.w);
  *(uint64_t*)(dst + (size_t)i * 4) = o.q;
}

// ---------------- transpose + convert: W[1024][1024] f32 -> Wt[n][k] bf16 ----------------
__global__ __launch_bounds__(256) void transpose_cvt(const float* __restrict__ W,
                                                     uint16_t* __restrict__ Wt) {
  __shared__ uint16_t tile[32][33];
  const int bx = blockIdx.x * 32;  // n
  const int by = blockIdx.y * 32;  // k
  const int tx = threadIdx.x;      // 0..31
  const int ty = threadIdx.y;      // 0..7
#pragma unroll
  for (int j = 0; j < 4; j++)
    tile[ty + j * 8][tx] = f2bf(W[(size_t)(by + ty + j * 8) * 1024 + bx + tx]);
  __syncthreads();
#pragma unroll
  for (int j = 0; j < 4; j++)
    Wt[(size_t)(bx + ty + j * 8) * 1024 + by + tx] = tile[tx][ty + j * 8];
}

// ---------------- GEMM: C[M][c] = A[M][K=1024] * Wt[c][K=1024]^T ----------------
// MODE 0: QKV projection, NBX=24 (N=3072): Q/K scatter [BH][S][64]; V scatter to
//         BLOCKED layout [BH][32 tiles][64 dh][64 s] (tile-contiguous for attn staging)
// MODE 1: out projection, NBX=8 (N=1024), fp32 C row-major
// 1-D grid (NBX*64 blocks). XCD-chunked supertile decode (T1 + L2 blocking).
template <int MODE, int NBX>
__global__ __launch_bounds__(256) void gemm_bt(const uint16_t* __restrict__ A,
                                               const uint16_t* __restrict__ Bt,
                                               uint16_t* __restrict__ O0,
                                               uint16_t* __restrict__ O1,
                                               uint16_t* __restrict__ O2,
                                               float* __restrict__ OF) {
  __shared__ uint16_t lds[2][128 * 32];  // [0]=A tile [128][32], [1]=B tile [128][32]
  const int tid = threadIdx.x;
  const int lane = tid & 63;
  const int wave = tid >> 6;
  const int wr = wave >> 1, wc = wave & 1;
  const int l15 = lane & 15, lg = lane >> 4;

  // XCD-chunked supertile decode
  const int nwg = NBX * 64;
  const int wg = ((int)blockIdx.x & 7) * (nwg >> 3) + ((int)blockIdx.x >> 3);
  const int st = wg >> 5, in32 = wg & 31;
  const int sy = in32 >> 2, sx = in32 & 3;
  const int stx = st % (NBX / 4), sty = st / (NBX / 4);
  const int row0 = (sty * 8 + sy) * 128;
  const int col0 = (stx * 4 + sx) * 128;

  f32x4 acc[4][4];
#pragma unroll
  for (int i = 0; i < 4; i++)
#pragma unroll
    for (int j = 0; j < 4; j++) acc[i][j] = f32x4{0.f, 0.f, 0.f, 0.f};

  const int srow = tid >> 2;          // 0..63
  const int scb = (tid & 3) * 16;     // byte offset within 64B row
  const char* Ab = (const char*)A;
  const char* Bb = (const char*)Bt;
  char* ldsA = (char*)&lds[0][0];
  char* ldsB = (char*)&lds[1][0];
  const int wbase = wave * 1024;      // wave-uniform LDS offset (HW adds lane*16)

  for (int kt = 0; kt < 1024; kt += 32) {
#pragma unroll
    for (int j = 0; j < 2; ++j) {
      const int r = j * 64 + srow;
      gload_lds16(Ab + ((size_t)(row0 + r) * 1024 + kt) * 2 + scb, ldsA + j * 4096 + wbase);
      gload_lds16(Bb + ((size_t)(col0 + r) * 1024 + kt) * 2 + scb, ldsB + j * 4096 + wbase);
    }
    __syncthreads();
    bf16x8 bfr[4];
#pragma unroll
    for (int ni = 0; ni < 4; ni++)
      bfr[ni] = *(const bf16x8*)&lds[1][(wc * 64 + ni * 16 + l15) * 32 + lg * 8];
#pragma unroll
    for (int mi = 0; mi < 4; mi++) {
      const bf16x8 afr = *(const bf16x8*)&lds[0][(wr * 64 + mi * 16 + l15) * 32 + lg * 8];
#pragma unroll
      for (int ni = 0; ni < 4; ni++) acc[mi][ni] = MFMA16(afr, bfr[ni], acc[mi][ni]);
    }
    __syncthreads();
  }

  // Epilogue. C/D layout: col = lane&15, row = (lane>>4)*4 + i  [m89-verified]
#pragma unroll
  for (int mi = 0; mi < 4; mi++) {
#pragma unroll
    for (int ni = 0; ni < 4; ni++) {
      const int c = col0 + wc * 64 + ni * 16 + l15;
      const int rbase = row0 + wr * 64 + mi * 16 + lg * 4;
#pragma unroll
      for (int i = 0; i < 4; i++) {
        const int r = rbase + i;
        const float v = acc[mi][ni][i];
        if (MODE == 0) {
          const int which = c >> 10, cc = c & 1023;
          const int h = cc >> 6, dh = cc & 63;
          const int b = r >> 11, s = r & 2047;
          const size_t hb = (size_t)(b * NH + h);
          if (which == 0)
            O0[(hb * NS + s) * 64 + dh] = f2bf(v * 0.18033688011112042f);  // (1/8)*log2(e)
          else if (which == 1)
            O1[(hb * NS + s) * 64 + dh] = f2bf(v);
          else  // blocked V: [BH][t=s>>6][dh][s&63]
            O2[(((hb * 32 + (s >> 6)) * 64 + dh) * 64) + (s & 63)] = f2bf(v);
        } else {
          OF[(size_t)r * 1024 + c] = v;
        }
      }
    }
  }
}

// ---- stage one (K,V) tile pair (8KB each, contiguous) into wave-private LDS ----
// Inverse-rotation source swizzle (rule 21): LDS dest linear (wave-uniform base +
// lane*16); per-lane global src byte zs = row*128 + ((chunk - row&7)&7)*16 so that a
// reader using chunk' = (chunk + row&7)&7 sees the logical row-major tile.
__device__ __forceinline__ void stage_kv(const char* __restrict__ Kg,
                                         const char* __restrict__ Vg,
                                         char* kl, char* vl, int lane) {
#pragma unroll
  for (int j = 0; j < 8; ++j) {
    const int y = j * 1024 + lane * 16;
    const int r = y >> 7;
    const int zs = (r << 7) | ((((y >> 4) - r) & 7) << 4);
    gload_lds16(Kg + zs, kl + j * 1024);
    gload_lds16(Vg + zs, vl + j * 1024);
  }
}

// ---- one 32-row attention unit: rows [32gp, 32gp+32) of head bh ----
// Dual 16-row chains A/B (same tmax, unconditional -> ILP-2). No-max softmax
// (logits ~N(0,1), |s*log2e| << 127): P=exp2(s), masked -> 0; denominator via
// ones-MFMA. K/V come from wave-private LDS tiles staged with coalesced
// global_load_lds (replaces 16-segment scattered register gathers: the round-16
// 9.4k-cy/iter latency). Fragment reads use chunk-rotation swizzle
// (chunk' = (chunk + row&7)&7) -> minimum 8-pass b128 bank pattern.
// Pipeline: read all 16 frags -> lgkmcnt(0) -> issue next tile's 16 loads ->
// compute (~600cy) hides stage latency; one vmcnt(0) per iteration.
// P path: k-major pX[k=64][q=16] with chunk-rotation (round-16, verified).
__device__ __forceinline__ void attn_unit(const uint16_t* __restrict__ Qh,
                                          const char* __restrict__ Kg,
                                          const char* __restrict__ Vg,
                                          uint16_t* __restrict__ Aout,
                                          int b, int h, int gp, int l15, int lg, int lane,
                                          char* kl, char* vl,
                                          uint16_t (*pX)[64][16]) {
  const int qbA = gp * 32;
  const int qbB = qbA + 16;
  const int tmax = gp >> 1;          // same last tile for both chains
  const int nfdA = (2 * gp) & 3;     // 0 or 2
  const int nfdB = nfdA + 1;

  // stage tile 0 (overlaps Q-fragment loads below)
  stage_kv(Kg, Vg, kl, vl, lane);

  const bf16x8 qfA0 = *(const bf16x8*)&Qh[(size_t)(qbA + l15) * 64 + lg * 8];
  const bf16x8 qfA1 = *(const bf16x8*)&Qh[(size_t)(qbA + l15) * 64 + 32 + lg * 8];
  const bf16x8 qfB0 = *(const bf16x8*)&Qh[(size_t)(qbB + l15) * 64 + lg * 8];
  const bf16x8 qfB1 = *(const bf16x8*)&Qh[(size_t)(qbB + l15) * 64 + 32 + lg * 8];

  const short one_bf = (short)0x3F80;  // bf16 1.0
  const bf16x8 ones = {one_bf, one_bf, one_bf, one_bf, one_bf, one_bf, one_bf, one_bf};

  const int rsw = l15 & 7;  // row&7 for both K rows (nf*16+l15) and V rows (df*16+l15)

  // P write col (u16): chunk' = (lg + (k>>2))&3 with (k>>2)&3 == l15>>2 (k=nf*16+l15)
  const int wcol = ((lg + (l15 >> 2)) & 3) * 4;
  // P tr-read per-lane swizzled addresses (round-16, verified)
  const int rr = l15 >> 2, cc0 = l15 & 3;
  const int rot = (2 * lg) & 3;
  const uint32_t pb = (uint32_t)(uintptr_t)&pX[0][0][0];
  const uint32_t addr0 = pb + (uint32_t)(lg * 256 + rr * 32 + (((cc0 + rot) & 3) * 8));
  const uint32_t addr1 = pb + (uint32_t)(lg * 256 + 128 + rr * 32 + (((cc0 + rot + 1) & 3) * 8));

  f32x4 oA[4], oB[4];
  f32x4 rsA = f32x4{0.f, 0.f, 0.f, 0.f};
  f32x4 rsB = f32x4{0.f, 0.f, 0.f, 0.f};
#pragma unroll
  for (int i = 0; i < 4; i++) {
    oA[i] = f32x4{0.f, 0.f, 0.f, 0.f};
    oB[i] = f32x4{0.f, 0.f, 0.f, 0.f};
  }

  for (int t = 0; t <= tmax; ++t) {
    // wait for this tile's staging to land
    asm volatile("s_waitcnt vmcnt(0)" ::: "memory");
    __builtin_amdgcn_sched_barrier(0);
    // read ALL K and V fragments into registers (rotation-swizzled ds_read_b128)
    bf16x8 kf[4][2], vf[4][2];
#pragma unroll
    for (int nf = 0; nf < 4; ++nf)
#pragma unroll
      for (int kk = 0; kk < 2; ++kk) {
        const int off = (nf * 16 + l15) * 128 + (((kk * 4 + lg) + rsw) & 7) * 16;
        kf[nf][kk] = *(const bf16x8*)(kl + off);
        vf[nf][kk] = *(const bf16x8*)(vl + off);
      }
    asm volatile("s_waitcnt lgkmcnt(0)" ::: "memory");
    __builtin_amdgcn_sched_barrier(0);
    // prefetch next tile (frags are in regs; overwrites the buffers)
    if (t < tmax) stage_kv(Kg + (size_t)(t + 1) * 8192, Vg + (size_t)(t + 1) * 8192, kl, vl, lane);

    const int nfmA = (t == tmax) ? nfdA : 3;
    const int nfmB = (t == tmax) ? nfdB : 3;
#pragma unroll
    for (int nf = 0; nf < 4; ++nf) {
      if (nf <= nfmB) {
        f32x4 a = f32x4{0.f, 0.f, 0.f, 0.f};
        a = MFMA16(qfB0, kf[nf][0], a);
        a = MFMA16(qfB1, kf[nf][1], a);
        if (t == tmax && nf == nfdB) {  // chain-B diagonal fragment: mask col > row
#pragma unroll
          for (int i = 0; i < 4; i++)
            if (l15 > lg * 4 + i) a[i] = -1e30f;
        }
        {
          const float e0 = exp2f(a[0]), e1 = exp2f(a[1]);
          const float e2 = exp2f(a[2]), e3 = exp2f(a[3]);
          *(uint64_t*)&pX[1][nf * 16 + l15][wcol] =
              ((uint64_t)pk2(e2, e3) << 32) | pk2(e0, e1);
        }
        if (nf <= nfmA) {
          f32x4 c = f32x4{0.f, 0.f, 0.f, 0.f};
          c = MFMA16(qfA0, kf[nf][0], c);
          c = MFMA16(qfA1, kf[nf][1], c);
          if (t == tmax && nf == nfdA) {
#pragma unroll
            for (int i = 0; i < 4; i++)
              if (l15 > lg * 4 + i) c[i] = -1e30f;
          }
          const float e0 = exp2f(c[0]), e1 = exp2f(c[1]);
          const float e2 = exp2f(c[2]), e3 = exp2f(c[3]);
          *(uint64_t*)&pX[0][nf * 16 + l15][wcol] =
              ((uint64_t)pk2(e2, e3) << 32) | pk2(e0, e1);
        } else {
          *(uint64_t*)&pX[0][nf * 16 + l15][wcol] = 0ull;
        }
      } else {
        *(uint64_t*)&pX[0][nf * 16 + l15][wcol] = 0ull;
        *(uint64_t*)&pX[1][nf * 16 + l15][wcol] = 0ull;
      }
    }
    // transpose-read P fragments (waitcnt inside; MFMA data-depends on outputs)
    u32x2 a0, a1, a2, a3, b0, b1, b2, b3;
    asm volatile(
        "ds_read_b64_tr_b16 %0, %8\n\t"
        "ds_read_b64_tr_b16 %1, %9\n\t"
        "ds_read_b64_tr_b16 %2, %8 offset:1024\n\t"
        "ds_read_b64_tr_b16 %3, %9 offset:1024\n\t"
        "ds_read_b64_tr_b16 %4, %8 offset:2048\n\t"
        "ds_read_b64_tr_b16 %5, %9 offset:2048\n\t"
        "ds_read_b64_tr_b16 %6, %8 offset:3072\n\t"
        "ds_read_b64_tr_b16 %7, %9 offset:3072\n\t"
        "s_waitcnt lgkmcnt(0)"
        : "=&v"(a0), "=&v"(a1), "=&v"(a2), "=&v"(a3),
          "=&v"(b0), "=&v"(b1), "=&v"(b2), "=&v"(b3)
        : "v"(addr0), "v"(addr1)
        : "memory");
    union { u32x2 u2[2]; bf16x8 v8; } uA0, uA1, uB0, uB1;
    uA0.u2[0] = a0; uA0.u2[1] = a1;  // k = lg*8 + 0..7
    uA1.u2[0] = a2; uA1.u2[1] = a3;  // k = 32 + lg*8 + 0..7
    uB0.u2[0] = b0; uB0.u2[1] = b1;
    uB1.u2[0] = b2; uB1.u2[1] = b3;
    const bf16x8 paA0 = uA0.v8, paA1 = uA1.v8;
    const bf16x8 paB0 = uB0.v8, paB1 = uB1.v8;
    rsA = MFMA16(paA0, ones, rsA);
    rsA = MFMA16(paA1, ones, rsA);
    rsB = MFMA16(paB0, ones, rsB);
    rsB = MFMA16(paB1, ones, rsB);
#pragma unroll
    for (int df = 0; df < 4; ++df) {
      oA[df] = MFMA16(paA0, vf[df][0], oA[df]);
      oA[df] = MFMA16(paA1, vf[df][1], oA[df]);
      oB[df] = MFMA16(paB0, vf[df][0], oB[df]);
      oB[df] = MFMA16(paB1, vf[df][1], oB[df]);
    }
  }

#pragma unroll
  for (int df = 0; df < 4; ++df) {
#pragma unroll
    for (int i = 0; i < 4; i++) {
      const int qA = qbA + lg * 4 + i;
      const int qB = qbB + lg * 4 + i;
      Aout[((size_t)(b * NS + qA)) * 1024 + h * 64 + df * 16 + l15] = f2bf(oA[df][i] / rsA[i]);
      Aout[((size_t)(b * NS + qB)) * 1024 + h * 64 + df * 16 + l15] = f2bf(oB[df][i] / rsB[i]);
    }
  }
}

// ---------------- causal flash attention (wave = two sequential balanced units) ----------------
// grid 512 blocks x 4 waves = 2048 waves. Block decode: xcd = bid&7, sp = (bid>>3)&3,
// gblk = bid>>5; wave w -> g = gblk*4 + w (0..63).
// Wave runs unit (bh = (2sp)<<3|xcd, gp = g) then unit (bh = (2sp+1)<<3|xcd, gp = 63-g):
// total iterations = 33..34 for EVERY wave -> no stragglers; both heads on one XCD.
// LDS/wave: 8KB K-stage + 8KB V-stage + 4KB P = 20KB; 80KB/block -> 2 blocks/CU.
__global__ __launch_bounds__(256) void attn_fwd(const uint16_t* __restrict__ Q,
                                                const uint16_t* __restrict__ K,
                                                const uint16_t* __restrict__ Vt,
                                                uint16_t* __restrict__ Aout) {
  const int bid = blockIdx.x;
  const int xcd = bid & 7;
  const int sp = (bid >> 3) & 3;
  const int gblk = bid >> 5;  // 0..15

  const int w = threadIdx.x >> 6;
  const int lane = threadIdx.x & 63;
  const int l15 = lane & 15, lg = lane >> 4;
  const int g = gblk * 4 + w;  // 0..63

  __shared__ __align__(16) uint16_t plds[4][2][64][16];  // P buffers (16 KB)
  __shared__ __align__(16) char kstage[4][8192];         // K tiles  (32 KB)
  __shared__ __align__(16) char vstage[4][8192];         // V tiles  (32 KB)

  for (int seg = 0; seg < 2; ++seg) {
    const int slot = sp * 2 + seg;
    const int bh = (slot << 3) | xcd;
    const int gp = seg ? (63 - g) : g;
    const uint16_t* Qh = Q + (size_t)bh * (NS * 64);
    const char* Kg = (const char*)(K + (size_t)bh * (NS * 64));        // tiles at t*8192 B
    const char* Vg = (const char*)(Vt + (size_t)bh * (32 * 64 * 64));  // blocked tiles, t*8192 B
    attn_unit(Qh, Kg, Vg, Aout, bh >> 4, bh & 15, gp, l15, lg, lane,
              kstage[w], vstage[w], plds[w]);
  }
}

extern "C" void kernel_launch(void* const* d_in, const int* in_sizes, int n_in,
                              void* d_out, int out_size, void* d_ws, size_t ws_size,
                              hipStream_t stream) {
  const float* x = (const float*)d_in[0];
  const float* Wq = (const float*)d_in[1];
  const float* Wk = (const float*)d_in[2];
  const float* Wv = (const float*)d_in[3];
  const float* Wo = (const float*)d_in[4];
  float* out = (float*)d_out;

  char* ws = (char*)d_ws;
  uint16_t* xb = (uint16_t*)(ws);                        // 16 MB  (reused as attn buffer)
  uint16_t* Wt3 = (uint16_t*)(ws + (16u << 20));         // 6 MB   [3][1024][1024] (n-major)
  uint16_t* Wot = (uint16_t*)(ws + (22u << 20));         // 2 MB
  uint16_t* Qb = (uint16_t*)(ws + (24u << 20));          // 16 MB  [BH][S][64]
  uint16_t* Kb = (uint16_t*)(ws + (40u << 20));          // 16 MB  [BH][S][64]
  uint16_t* Vt = (uint16_t*)(ws + (56u << 20));          // 16 MB  blocked [BH][32][64][64]
  uint16_t* attn = xb;                                   // total 72 MB

  cvt_bf16_kernel<<<8192, 256, 0, stream>>>(x, xb, (NB * NS * ND) / 4);
  dim3 tb(32, 8);
  transpose_cvt<<<dim3(32, 32), tb, 0, stream>>>(Wq, Wt3);
  transpose_cvt<<<dim3(32, 32), tb, 0, stream>>>(Wk, Wt3 + (1u << 20));
  transpose_cvt<<<dim3(32, 32), tb, 0, stream>>>(Wv, Wt3 + (2u << 20));
  transpose_cvt<<<dim3(32, 32), tb, 0, stream>>>(Wo, Wot);

  gemm_bt<0, 24><<<1536, 256, 0, stream>>>(xb, Wt3, Qb, Kb, Vt, nullptr);
  attn_fwd<<<512, 256, 0, stream>>>(Qb, Kb, Vt, attn);
  gemm_bt<1, 8><<<512, 256, 0, stream>>>(attn, Wot, nullptr, nullptr, nullptr, out);
}

// Round 18
// 196.042 us; speedup vs baseline: 1.5171x; 1.0017x over previous
//
#include <hip/hip_runtime.h>
#include <stdint.h>

// Shapes (fixed): B=4, S=2048, D=1024, H=16, DH=64
#define NB 4
#define NS 2048
#define ND 1024
#define NH 16
#define NDH 64

typedef __attribute__((ext_vector_type(8))) short bf16x8;
typedef __attribute__((ext_vector_type(4))) float f32x4;
typedef __attribute__((ext_vector_type(2))) unsigned int u32x2;

#define MFMA16(a, b, c) __builtin_amdgcn_mfma_f32_16x16x32_bf16((a), (b), (c), 0, 0, 0)

__device__ __forceinline__ uint16_t f2bf(float f) {
  uint32_t u = __builtin_bit_cast(uint32_t, f);
  return (uint16_t)((u + 0x7FFFu + ((u >> 16) & 1u)) >> 16);
}

// truncating bf16x2 pack (for P values; downward bias cancels in o/rs ratio)
__device__ __forceinline__ uint32_t pk2(float lo, float hi) {
  return (__builtin_bit_cast(uint32_t, hi) & 0xFFFF0000u) |
         (__builtin_bit_cast(uint32_t, lo) >> 16);
}

__device__ __forceinline__ void gload_lds16(const void* g, void* l) {
  __builtin_amdgcn_global_load_lds(
      (const __attribute__((address_space(1))) uint32_t*)(uintptr_t)g,
      (__attribute__((address_space(3))) uint32_t*)(uintptr_t)l, 16, 0, 0);
}

// ---------------- fp32 -> bf16 convert (x) ----------------
__global__ __launch_bounds__(256) void cvt_bf16_kernel(const float* __restrict__ src,
                                                       uint16_t* __restrict__ dst, int n4) {
  int i = blockIdx.x * 256 + threadIdx.x;
  if (i >= n4) return;
  const float4 f = *(const float4*)(src + (size_t)i * 4);
  union { uint16_t u[4]; uint64_t q; } o;
  o.u[0] = f2bf(f.x); o.u[1] = f2bf(f.y); o.u[2] = f2bf(f.z); o.u[3] = f2bf(f.w);
  *(uint64_t*)(dst + (size_t)i * 4) = o.q;
}

// ---------------- transpose + convert: W[1024][1024] f32 -> Wt[n][k] bf16 ----------------
__global__ __launch_bounds__(256) void transpose_cvt(const float* __restrict__ W,
                                                     uint16_t* __restrict__ Wt) {
  __shared__ uint16_t tile[32][33];
  const int bx = blockIdx.x * 32;  // n
  const int by = blockIdx.y * 32;  // k
  const int tx = threadIdx.x;      // 0..31
  const int ty = threadIdx.y;      // 0..7
#pragma unroll
  for (int j = 0; j < 4; j++)
    tile[ty + j * 8][tx] = f2bf(W[(size_t)(by + ty + j * 8) * 1024 + bx + tx]);
  __syncthreads();
#pragma unroll
  for (int j = 0; j < 4; j++)
    Wt[(size_t)(bx + ty + j * 8) * 1024 + by + tx] = tile[tx][ty + j * 8];
}

// ---------------- GEMM: C[M][c] = A[M][K=1024] * Wt[c][K=1024]^T ----------------
// 128x128 tile, BK=64, double-buffered LDS, T3 minimum-2-phase loop:
//   STAGE(buf^1, t+1) -> ds_read+MFMA(buf, t) -> one __syncthreads (vmcnt0+barrier).
// Loads for t+1 overlap t's entire compute phase (vs the old stage->drain->compute).
// LDS tiles use chunk-rotation swizzle (chunk' = (chunk + row)&7 within the 128B row;
// staged via inverse-rotated per-lane global source, rule 21) -> 2-way read conflicts.
// MODE 0: QKV projection, NBX=24: Q/K scatter [BH][S][64]; V scatter to BLOCKED
//         layout [BH][32 tiles][64 dh][64 s]. MODE 1: out projection, NBX=8, fp32 C.
// 1-D grid (NBX*64 blocks). XCD-chunked supertile decode (T1 + L2 blocking).
template <int MODE, int NBX>
__global__ __launch_bounds__(256) void gemm_bt(const uint16_t* __restrict__ A,
                                               const uint16_t* __restrict__ Bt,
                                               uint16_t* __restrict__ O0,
                                               uint16_t* __restrict__ O1,
                                               uint16_t* __restrict__ O2,
                                               float* __restrict__ OF) {
  __shared__ uint16_t lds[2][2][128 * 64];  // [buf][A/B][128 rows x 64 cols] = 64 KB
  const int tid = threadIdx.x;
  const int lane = tid & 63;
  const int wave = tid >> 6;
  const int wr = wave >> 1, wc = wave & 1;
  const int l15 = lane & 15, lg = lane >> 4;

  // XCD-chunked supertile decode
  const int nwg = NBX * 64;
  const int wg = ((int)blockIdx.x & 7) * (nwg >> 3) + ((int)blockIdx.x >> 3);
  const int st = wg >> 5, in32 = wg & 31;
  const int sy = in32 >> 2, sx = in32 & 3;
  const int stx = st % (NBX / 4), sty = st / (NBX / 4);
  const int row0 = (sty * 8 + sy) * 128;
  const int col0 = (stx * 4 + sx) * 128;

  f32x4 acc[4][4];
#pragma unroll
  for (int i = 0; i < 4; i++)
#pragma unroll
    for (int j = 0; j < 4; j++) acc[i][j] = f32x4{0.f, 0.f, 0.f, 0.f};

  const char* Ag = (const char*)A + (size_t)row0 * 2048;  // rows of A (2048 B stride)
  const char* Bg = (const char*)Bt + (size_t)col0 * 2048;

  // staging geometry: 4 gload_lds per tile per operand; instr j covers rows j*32..+31.
  // dest byte (tile-local) y = j*4096 + tid*16 -> row r = j*32 + (tid>>3), chunk tid&7.
  // inverse-rotation source chunk: csrc = ((tid&7) - (tid>>3)) & 7  (j*32 == 0 mod 8)
  const int srr = tid >> 3;
  const int csrc = ((tid & 7) - srr) & 7;
  uint16_t* ldsA0 = &lds[0][0][0];

#define STAGE_TILE(buf, t)                                                          \
  {                                                                                 \
    char* la = (char*)&lds[buf][0][0] + wave * 1024;                                \
    char* lb = (char*)&lds[buf][1][0] + wave * 1024;                                \
    _Pragma("unroll") for (int j = 0; j < 4; ++j) {                                 \
      const size_t off = (size_t)(j * 32 + srr) * 2048 + (size_t)(t) * 128 + csrc * 16; \
      gload_lds16(Ag + off, la + j * 4096);                                         \
      gload_lds16(Bg + off, lb + j * 4096);                                         \
    }                                                                               \
  }

  STAGE_TILE(0, 0);
  __syncthreads();

  int cur = 0;
  for (int t = 0; t < 16; ++t) {
    if (t < 15) STAGE_TILE(cur ^ 1, t + 1);  // loads fly during this tile's compute
    const char* cA = (const char*)&lds[cur][0][0];
    const char* cB = (const char*)&lds[cur][1][0];
    bf16x8 af[4][2], bfr[4][2];
#pragma unroll
    for (int mi = 0; mi < 4; mi++) {
      const int row = wr * 64 + mi * 16 + l15;
#pragma unroll
      for (int ks = 0; ks < 2; ks++) {
        const int ch = (ks * 4 + lg + (l15 & 7)) & 7;  // rotation swizzle
        af[mi][ks] = *(const bf16x8*)(cA + row * 128 + ch * 16);
      }
    }
#pragma unroll
    for (int ni = 0; ni < 4; ni++) {
      const int row = wc * 64 + ni * 16 + l15;
#pragma unroll
      for (int ks = 0; ks < 2; ks++) {
        const int ch = (ks * 4 + lg + (l15 & 7)) & 7;
        bfr[ni][ks] = *(const bf16x8*)(cB + row * 128 + ch * 16);
      }
    }
#pragma unroll
    for (int ks = 0; ks < 2; ks++)
#pragma unroll
      for (int mi = 0; mi < 4; mi++)
#pragma unroll
        for (int ni = 0; ni < 4; ni++)
          acc[mi][ni] = MFMA16(af[mi][ks], bfr[ni][ks], acc[mi][ni]);
    __syncthreads();  // vmcnt(0)+lgkmcnt(0)+barrier: t+1 resident, all reads of cur done
    cur ^= 1;
  }
  (void)ldsA0;

  // Epilogue. C/D layout: col = lane&15, row = (lane>>4)*4 + i  [m89-verified]
#pragma unroll
  for (int mi = 0; mi < 4; mi++) {
#pragma unroll
    for (int ni = 0; ni < 4; ni++) {
      const int c = col0 + wc * 64 + ni * 16 + l15;
      const int rbase = row0 + wr * 64 + mi * 16 + lg * 4;
#pragma unroll
      for (int i = 0; i < 4; i++) {
        const int r = rbase + i;
        const float v = acc[mi][ni][i];
        if (MODE == 0) {
          const int which = c >> 10, cc = c & 1023;
          const int h = cc >> 6, dh = cc & 63;
          const int b = r >> 11, s = r & 2047;
          const size_t hb = (size_t)(b * NH + h);
          if (which == 0)
            O0[(hb * NS + s) * 64 + dh] = f2bf(v * 0.18033688011112042f);  // (1/8)*log2(e)
          else if (which == 1)
            O1[(hb * NS + s) * 64 + dh] = f2bf(v);
          else  // blocked V: [BH][t=s>>6][dh][s&63]
            O2[(((hb * 32 + (s >> 6)) * 64 + dh) * 64) + (s & 63)] = f2bf(v);
        } else {
          OF[(size_t)r * 1024 + c] = v;
        }
      }
    }
  }
#undef STAGE_TILE
}

// ---- stage one (K,V) tile pair (8KB each, contiguous) into wave-private LDS ----
// Inverse-rotation source swizzle (rule 21): LDS dest linear (wave-uniform base +
// lane*16); per-lane global src byte zs = row*128 + ((chunk - row&7)&7)*16 so that a
// reader using chunk' = (chunk + row&7)&7 sees the logical row-major tile.
__device__ __forceinline__ void stage_kv(const char* __restrict__ Kg,
                                         const char* __restrict__ Vg,
                                         char* kl, char* vl, int lane) {
#pragma unroll
  for (int j = 0; j < 8; ++j) {
    const int y = j * 1024 + lane * 16;
    const int r = y >> 7;
    const int zs = (r << 7) | ((((y >> 4) - r) & 7) << 4);
    gload_lds16(Kg + zs, kl + j * 1024);
    gload_lds16(Vg + zs, vl + j * 1024);
  }
}

// ---- one 32-row attention unit: rows [32gp, 32gp+32) of head bh ----
// Dual 16-row chains A/B (same tmax, unconditional -> ILP-2). No-max softmax
// (logits ~N(0,1), |s*log2e| << 127): P=exp2(s), masked -> 0; denominator via
// ones-MFMA. K/V from wave-private LDS tiles staged with coalesced global_load_lds;
// fragment reads use chunk-rotation swizzle (chunk' = (chunk + row&7)&7).
// Pipeline: vmcnt(0) -> read all 16 frags -> lgkmcnt(0) -> issue next tile's loads ->
// compute hides stage latency. P path: k-major pX[k=64][q=16] with chunk-rotation +
// ds_read_b64_tr_b16 (round-16, verified).
__device__ __forceinline__ void attn_unit(const uint16_t* __restrict__ Qh,
                                          const char* __restrict__ Kg,
                                          const char* __restrict__ Vg,
                                          uint16_t* __restrict__ Aout,
                                          int b, int h, int gp, int l15, int lg, int lane,
                                          char* kl, char* vl,
                                          uint16_t (*pX)[64][16]) {
  const int qbA = gp * 32;
  const int qbB = qbA + 16;
  const int tmax = gp >> 1;          // same last tile for both chains
  const int nfdA = (2 * gp) & 3;     // 0 or 2
  const int nfdB = nfdA + 1;

  // stage tile 0 (overlaps Q-fragment loads below)
  stage_kv(Kg, Vg, kl, vl, lane);

  const bf16x8 qfA0 = *(const bf16x8*)&Qh[(size_t)(qbA + l15) * 64 + lg * 8];
  const bf16x8 qfA1 = *(const bf16x8*)&Qh[(size_t)(qbA + l15) * 64 + 32 + lg * 8];
  const bf16x8 qfB0 = *(const bf16x8*)&Qh[(size_t)(qbB + l15) * 64 + lg * 8];
  const bf16x8 qfB1 = *(const bf16x8*)&Qh[(size_t)(qbB + l15) * 64 + 32 + lg * 8];

  const short one_bf = (short)0x3F80;  // bf16 1.0
  const bf16x8 ones = {one_bf, one_bf, one_bf, one_bf, one_bf, one_bf, one_bf, one_bf};

  const int rsw = l15 & 7;  // row&7 for both K rows (nf*16+l15) and V rows (df*16+l15)

  // P write col (u16): chunk' = (lg + (k>>2))&3 with (k>>2)&3 == l15>>2 (k=nf*16+l15)
  const int wcol = ((lg + (l15 >> 2)) & 3) * 4;
  // P tr-read per-lane swizzled addresses (round-16, verified)
  const int rr = l15 >> 2, cc0 = l15 & 3;
  const int rot = (2 * lg) & 3;
  const uint32_t pb = (uint32_t)(uintptr_t)&pX[0][0][0];
  const uint32_t addr0 = pb + (uint32_t)(lg * 256 + rr * 32 + (((cc0 + rot) & 3) * 8));
  const uint32_t addr1 = pb + (uint32_t)(lg * 256 + 128 + rr * 32 + (((cc0 + rot + 1) & 3) * 8));

  f32x4 oA[4], oB[4];
  f32x4 rsA = f32x4{0.f, 0.f, 0.f, 0.f};
  f32x4 rsB = f32x4{0.f, 0.f, 0.f, 0.f};
#pragma unroll
  for (int i = 0; i < 4; i++) {
    oA[i] = f32x4{0.f, 0.f, 0.f, 0.f};
    oB[i] = f32x4{0.f, 0.f, 0.f, 0.f};
  }

  for (int t = 0; t <= tmax; ++t) {
    // wait for this tile's staging to land
    asm volatile("s_waitcnt vmcnt(0)" ::: "memory");
    __builtin_amdgcn_sched_barrier(0);
    // read ALL K and V fragments into registers (rotation-swizzled ds_read_b128)
    bf16x8 kf[4][2], vf[4][2];
#pragma unroll
    for (int nf = 0; nf < 4; ++nf)
#pragma unroll
      for (int kk = 0; kk < 2; ++kk) {
        const int off = (nf * 16 + l15) * 128 + (((kk * 4 + lg) + rsw) & 7) * 16;
        kf[nf][kk] = *(const bf16x8*)(kl + off);
        vf[nf][kk] = *(const bf16x8*)(vl + off);
      }
    asm volatile("s_waitcnt lgkmcnt(0)" ::: "memory");
    __builtin_amdgcn_sched_barrier(0);
    // prefetch next tile (frags are in regs; overwrites the buffers)
    if (t < tmax) stage_kv(Kg + (size_t)(t + 1) * 8192, Vg + (size_t)(t + 1) * 8192, kl, vl, lane);

    const int nfmA = (t == tmax) ? nfdA : 3;
    const int nfmB = (t == tmax) ? nfdB : 3;
#pragma unroll
    for (int nf = 0; nf < 4; ++nf) {
      if (nf <= nfmB) {
        f32x4 a = f32x4{0.f, 0.f, 0.f, 0.f};
        a = MFMA16(qfB0, kf[nf][0], a);
        a = MFMA16(qfB1, kf[nf][1], a);
        if (t == tmax && nf == nfdB) {  // chain-B diagonal fragment: mask col > row
#pragma unroll
          for (int i = 0; i < 4; i++)
            if (l15 > lg * 4 + i) a[i] = -1e30f;
        }
        {
          const float e0 = exp2f(a[0]), e1 = exp2f(a[1]);
          const float e2 = exp2f(a[2]), e3 = exp2f(a[3]);
          *(uint64_t*)&pX[1][nf * 16 + l15][wcol] =
              ((uint64_t)pk2(e2, e3) << 32) | pk2(e0, e1);
        }
        if (nf <= nfmA) {
          f32x4 c = f32x4{0.f, 0.f, 0.f, 0.f};
          c = MFMA16(qfA0, kf[nf][0], c);
          c = MFMA16(qfA1, kf[nf][1], c);
          if (t == tmax && nf == nfdA) {
#pragma unroll
            for (int i = 0; i < 4; i++)
              if (l15 > lg * 4 + i) c[i] = -1e30f;
          }
          const float e0 = exp2f(c[0]), e1 = exp2f(c[1]);
          const float e2 = exp2f(c[2]), e3 = exp2f(c[3]);
          *(uint64_t*)&pX[0][nf * 16 + l15][wcol] =
              ((uint64_t)pk2(e2, e3) << 32) | pk2(e0, e1);
        } else {
          *(uint64_t*)&pX[0][nf * 16 + l15][wcol] = 0ull;
        }
      } else {
        *(uint64_t*)&pX[0][nf * 16 + l15][wcol] = 0ull;
        *(uint64_t*)&pX[1][nf * 16 + l15][wcol] = 0ull;
      }
    }
    // transpose-read P fragments (waitcnt inside; MFMA data-depends on outputs)
    u32x2 a0, a1, a2, a3, b0, b1, b2, b3;
    asm volatile(
        "ds_read_b64_tr_b16 %0, %8\n\t"
        "ds_read_b64_tr_b16 %1, %9\n\t"
        "ds_read_b64_tr_b16 %2, %8 offset:1024\n\t"
        "ds_read_b64_tr_b16 %3, %9 offset:1024\n\t"
        "ds_read_b64_tr_b16 %4, %8 offset:2048\n\t"
        "ds_read_b64_tr_b16 %5, %9 offset:2048\n\t"
        "ds_read_b64_tr_b16 %6, %8 offset:3072\n\t"
        "ds_read_b64_tr_b16 %7, %9 offset:3072\n\t"
        "s_waitcnt lgkmcnt(0)"
        : "=&v"(a0), "=&v"(a1), "=&v"(a2), "=&v"(a3),
          "=&v"(b0), "=&v"(b1), "=&v"(b2), "=&v"(b3)
        : "v"(addr0), "v"(addr1)
        : "memory");
    union { u32x2 u2[2]; bf16x8 v8; } uA0, uA1, uB0, uB1;
    uA0.u2[0] = a0; uA0.u2[1] = a1;  // k = lg*8 + 0..7
    uA1.u2[0] = a2; uA1.u2[1] = a3;  // k = 32 + lg*8 + 0..7
    uB0.u2[0] = b0; uB0.u2[1] = b1;
    uB1.u2[0] = b2; uB1.u2[1] = b3;
    const bf16x8 paA0 = uA0.v8, paA1 = uA1.v8;
    const bf16x8 paB0 = uB0.v8, paB1 = uB1.v8;
    rsA = MFMA16(paA0, ones, rsA);
    rsA = MFMA16(paA1, ones, rsA);
    rsB = MFMA16(paB0, ones, rsB);
    rsB = MFMA16(paB1, ones, rsB);
#pragma unroll
    for (int df = 0; df < 4; ++df) {
      oA[df] = MFMA16(paA0, vf[df][0], oA[df]);
      oA[df] = MFMA16(paA1, vf[df][1], oA[df]);
      oB[df] = MFMA16(paB0, vf[df][0], oB[df]);
      oB[df] = MFMA16(paB1, vf[df][1], oB[df]);
    }
  }

#pragma unroll
  for (int df = 0; df < 4; ++df) {
#pragma unroll
    for (int i = 0; i < 4; i++) {
      const int qA = qbA + lg * 4 + i;
      const int qB = qbB + lg * 4 + i;
      Aout[((size_t)(b * NS + qA)) * 1024 + h * 64 + df * 16 + l15] = f2bf(oA[df][i] / rsA[i]);
      Aout[((size_t)(b * NS + qB)) * 1024 + h * 64 + df * 16 + l15] = f2bf(oB[df][i] / rsB[i]);
    }
  }
}

// ---------------- causal flash attention (wave = two sequential balanced units) ----------------
// grid 512 blocks x 4 waves = 2048 waves. Block decode: xcd = bid&7, sp = (bid>>3)&3,
// gblk = bid>>5; wave w -> g = gblk*4 + w (0..63).
// Wave runs unit (bh = (2sp)<<3|xcd, gp = g) then unit (bh = (2sp+1)<<3|xcd, gp = 63-g):
// total iterations = 33..34 for EVERY wave -> no stragglers; both heads on one XCD.
// LDS/wave: 8KB K-stage + 8KB V-stage + 4KB P = 20KB; 80KB/block -> 2 blocks/CU.
__global__ __launch_bounds__(256) void attn_fwd(const uint16_t* __restrict__ Q,
                                                const uint16_t* __restrict__ K,
                                                const uint16_t* __restrict__ Vt,
                                                uint16_t* __restrict__ Aout) {
  const int bid = blockIdx.x;
  const int xcd = bid & 7;
  const int sp = (bid >> 3) & 3;
  const int gblk = bid >> 5;  // 0..15

  const int w = threadIdx.x >> 6;
  const int lane = threadIdx.x & 63;
  const int l15 = lane & 15, lg = lane >> 4;
  const int g = gblk * 4 + w;  // 0..63

  __shared__ __align__(16) uint16_t plds[4][2][64][16];  // P buffers (16 KB)
  __shared__ __align__(16) char kstage[4][8192];         // K tiles  (32 KB)
  __shared__ __align__(16) char vstage[4][8192];         // V tiles  (32 KB)

  for (int seg = 0; seg < 2; ++seg) {
    const int slot = sp * 2 + seg;
    const int bh = (slot << 3) | xcd;
    const int gp = seg ? (63 - g) : g;
    const uint16_t* Qh = Q + (size_t)bh * (NS * 64);
    const char* Kg = (const char*)(K + (size_t)bh * (NS * 64));        // tiles at t*8192 B
    const char* Vg = (const char*)(Vt + (size_t)bh * (32 * 64 * 64));  // blocked tiles, t*8192 B
    attn_unit(Qh, Kg, Vg, Aout, bh >> 4, bh & 15, gp, l15, lg, lane,
              kstage[w], vstage[w], plds[w]);
  }
}

extern "C" void kernel_launch(void* const* d_in, const int* in_sizes, int n_in,
                              void* d_out, int out_size, void* d_ws, size_t ws_size,
                              hipStream_t stream) {
  const float* x = (const float*)d_in[0];
  const float* Wq = (const float*)d_in[1];
  const float* Wk = (const float*)d_in[2];
  const float* Wv = (const float*)d_in[3];
  const float* Wo = (const float*)d_in[4];
  float* out = (float*)d_out;

  char* ws = (char*)d_ws;
  uint16_t* xb = (uint16_t*)(ws);                        // 16 MB  (reused as attn buffer)
  uint16_t* Wt3 = (uint16_t*)(ws + (16u << 20));         // 6 MB   [3][1024][1024] (n-major)
  uint16_t* Wot = (uint16_t*)(ws + (22u << 20));         // 2 MB
  uint16_t* Qb = (uint16_t*)(ws + (24u << 20));          // 16 MB  [BH][S][64]
  uint16_t* Kb = (uint16_t*)(ws + (40u << 20));          // 16 MB  [BH][S][64]
  uint16_t* Vt = (uint16_t*)(ws + (56u << 20));          // 16 MB  blocked [BH][32][64][64]
  uint16_t* attn = xb;                                   // total 72 MB

  cvt_bf16_kernel<<<8192, 256, 0, stream>>>(x, xb, (NB * NS * ND) / 4);
  dim3 tb(32, 8);
  transpose_cvt<<<dim3(32, 32), tb, 0, stream>>>(Wq, Wt3);
  transpose_cvt<<<dim3(32, 32), tb, 0, stream>>>(Wk, Wt3 + (1u << 20));
  transpose_cvt<<<dim3(32, 32), tb, 0, stream>>>(Wv, Wt3 + (2u << 20));
  transpose_cvt<<<dim3(32, 32), tb, 0, stream>>>(Wo, Wot);

  gemm_bt<0, 24><<<1536, 256, 0, stream>>>(xb, Wt3, Qb, Kb, Vt, nullptr);
  attn_fwd<<<512, 256, 0, stream>>>(Qb, Kb, Vt, attn);
  gemm_bt<1, 8><<<512, 256, 0, stream>>>(attn, Wot, nullptr, nullptr, nullptr, out);
}

// Round 19
// 184.964 us; speedup vs baseline: 1.6080x; 1.0599x over previous
//
#include <hip/hip_runtime.h>
#include <stdint.h>

// Shapes (fixed): B=4, S=2048, D=1024, H=16, DH=64
#define NB 4
#define NS 2048
#define ND 1024
#define NH 16
#define NDH 64

typedef __attribute__((ext_vector_type(8))) short bf16x8;
typedef __attribute__((ext_vector_type(4))) float f32x4;
typedef __attribute__((ext_vector_type(2))) unsigned int u32x2;

#define MFMA16(a, b, c) __builtin_amdgcn_mfma_f32_16x16x32_bf16((a), (b), (c), 0, 0, 0)

__device__ __forceinline__ uint16_t f2bf(float f) {
  uint32_t u = __builtin_bit_cast(uint32_t, f);
  return (uint16_t)((u + 0x7FFFu + ((u >> 16) & 1u)) >> 16);
}

// truncating bf16x2 pack (for P values; downward bias cancels in o/rs ratio)
__device__ __forceinline__ uint32_t pk2(float lo, float hi) {
  return (__builtin_bit_cast(uint32_t, hi) & 0xFFFF0000u) |
         (__builtin_bit_cast(uint32_t, lo) >> 16);
}

__device__ __forceinline__ void gload_lds16(const void* g, void* l) {
  __builtin_amdgcn_global_load_lds(
      (const __attribute__((address_space(1))) uint32_t*)(uintptr_t)g,
      (__attribute__((address_space(3))) uint32_t*)(uintptr_t)l, 16, 0, 0);
}

// ---------------- fused prep: 4 weight transposes + x convert, ONE launch ----------------
// blocks 0..4095: weight transpose-convert (which = bid>>10, 32x32 tile = bid&1023)
// blocks 4096..12287: x fp32 -> bf16 (float4-vectorized)
__global__ __launch_bounds__(256) void prep_kernel(const float* __restrict__ x,
                                                   const float* __restrict__ Wq,
                                                   const float* __restrict__ Wk,
                                                   const float* __restrict__ Wv,
                                                   const float* __restrict__ Wo,
                                                   uint16_t* __restrict__ xb,
                                                   uint16_t* __restrict__ Wt3,
                                                   uint16_t* __restrict__ Wot) {
  const int bid = blockIdx.x;
  if (bid < 4096) {
    __shared__ uint16_t tile[32][33];
    const int which = bid >> 10;
    const int tl = bid & 1023;
    const int bx = (tl & 31) * 32;  // n
    const int by = (tl >> 5) * 32;  // k
    const int tx = threadIdx.x & 31;
    const int ty = threadIdx.x >> 5;  // 0..7
    const float* W = (which == 0) ? Wq : (which == 1) ? Wk : (which == 2) ? Wv : Wo;
    uint16_t* Wt = (which < 3) ? (Wt3 + (size_t)which * (1u << 20)) : Wot;
#pragma unroll
    for (int j = 0; j < 4; j++)
      tile[ty + j * 8][tx] = f2bf(W[(size_t)(by + ty + j * 8) * 1024 + bx + tx]);
    __syncthreads();
#pragma unroll
    for (int j = 0; j < 4; j++)
      Wt[(size_t)(bx + ty + j * 8) * 1024 + by + tx] = tile[tx][ty + j * 8];
  } else {
    const int i = (bid - 4096) * 256 + threadIdx.x;  // i < 2M (= NB*NS*ND/4)
    const float4 f = *(const float4*)(x + (size_t)i * 4);
    union { uint16_t u[4]; uint64_t q; } o;
    o.u[0] = f2bf(f.x); o.u[1] = f2bf(f.y); o.u[2] = f2bf(f.z); o.u[3] = f2bf(f.w);
    *(uint64_t*)(xb + (size_t)i * 4) = o.q;
  }
}

// ---------------- GEMM: C[M][c] = A[M][K=1024] * Wt[c][K=1024]^T ----------------
// 128x128 tile, BK=64, double-buffered LDS, T3 minimum-2-phase loop:
//   STAGE(buf^1, t+1) -> ds_read+MFMA(buf, t) -> one __syncthreads (vmcnt0+barrier).
// LDS tiles use chunk-rotation swizzle (chunk' = (chunk + row)&7 within the 128B row;
// staged via inverse-rotated per-lane global source, rule 21) -> 2-way read conflicts.
// MODE 0: QKV projection, NBX=24: Q/K scatter [BH][S][64]; V scatter to BLOCKED
//         layout [BH][32 tiles][64 dh][64 s]. MODE 1: out projection, NBX=8, fp32 C.
// 1-D grid (NBX*64 blocks). XCD-chunked supertile decode (T1 + L2 blocking).
template <int MODE, int NBX>
__global__ __launch_bounds__(256) void gemm_bt(const uint16_t* __restrict__ A,
                                               const uint16_t* __restrict__ Bt,
                                               uint16_t* __restrict__ O0,
                                               uint16_t* __restrict__ O1,
                                               uint16_t* __restrict__ O2,
                                               float* __restrict__ OF) {
  __shared__ uint16_t lds[2][2][128 * 64];  // [buf][A/B][128 rows x 64 cols] = 64 KB
  const int tid = threadIdx.x;
  const int lane = tid & 63;
  const int wave = tid >> 6;
  const int wr = wave >> 1, wc = wave & 1;
  const int l15 = lane & 15, lg = lane >> 4;

  // XCD-chunked supertile decode
  const int nwg = NBX * 64;
  const int wg = ((int)blockIdx.x & 7) * (nwg >> 3) + ((int)blockIdx.x >> 3);
  const int st = wg >> 5, in32 = wg & 31;
  const int sy = in32 >> 2, sx = in32 & 3;
  const int stx = st % (NBX / 4), sty = st / (NBX / 4);
  const int row0 = (sty * 8 + sy) * 128;
  const int col0 = (stx * 4 + sx) * 128;

  f32x4 acc[4][4];
#pragma unroll
  for (int i = 0; i < 4; i++)
#pragma unroll
    for (int j = 0; j < 4; j++) acc[i][j] = f32x4{0.f, 0.f, 0.f, 0.f};

  const char* Ag = (const char*)A + (size_t)row0 * 2048;  // rows of A (2048 B stride)
  const char* Bg = (const char*)Bt + (size_t)col0 * 2048;

  // staging geometry: 4 gload_lds per tile per operand; instr j covers rows j*32..+31.
  // dest byte (tile-local) y = j*4096 + tid*16 -> row r = j*32 + (tid>>3), chunk tid&7.
  // inverse-rotation source chunk: csrc = ((tid&7) - (tid>>3)) & 7  (j*32 == 0 mod 8)
  const int srr = tid >> 3;
  const int csrc = ((tid & 7) - srr) & 7;

#define STAGE_TILE(buf, t)                                                          \
  {                                                                                 \
    char* la = (char*)&lds[buf][0][0] + wave * 1024;                                \
    char* lb = (char*)&lds[buf][1][0] + wave * 1024;                                \
    _Pragma("unroll") for (int j = 0; j < 4; ++j) {                                 \
      const size_t off = (size_t)(j * 32 + srr) * 2048 + (size_t)(t) * 128 + csrc * 16; \
      gload_lds16(Ag + off, la + j * 4096);                                         \
      gload_lds16(Bg + off, lb + j * 4096);                                         \
    }                                                                               \
  }

  STAGE_TILE(0, 0);
  __syncthreads();

  int cur = 0;
  for (int t = 0; t < 16; ++t) {
    if (t < 15) STAGE_TILE(cur ^ 1, t + 1);  // loads fly during this tile's compute
    const char* cA = (const char*)&lds[cur][0][0];
    const char* cB = (const char*)&lds[cur][1][0];
    bf16x8 af[4][2], bfr[4][2];
#pragma unroll
    for (int mi = 0; mi < 4; mi++) {
      const int row = wr * 64 + mi * 16 + l15;
#pragma unroll
      for (int ks = 0; ks < 2; ks++) {
        const int ch = (ks * 4 + lg + (l15 & 7)) & 7;  // rotation swizzle
        af[mi][ks] = *(const bf16x8*)(cA + row * 128 + ch * 16);
      }
    }
#pragma unroll
    for (int ni = 0; ni < 4; ni++) {
      const int row = wc * 64 + ni * 16 + l15;
#pragma unroll
      for (int ks = 0; ks < 2; ks++) {
        const int ch = (ks * 4 + lg + (l15 & 7)) & 7;
        bfr[ni][ks] = *(const bf16x8*)(cB + row * 128 + ch * 16);
      }
    }
#pragma unroll
    for (int ks = 0; ks < 2; ks++)
#pragma unroll
      for (int mi = 0; mi < 4; mi++)
#pragma unroll
        for (int ni = 0; ni < 4; ni++)
          acc[mi][ni] = MFMA16(af[mi][ks], bfr[ni][ks], acc[mi][ni]);
    __syncthreads();  // vmcnt(0)+lgkmcnt(0)+barrier: t+1 resident, all reads of cur done
    cur ^= 1;
  }

  // Epilogue. C/D layout: col = lane&15, row = (lane>>4)*4 + i  [m89-verified]
#pragma unroll
  for (int mi = 0; mi < 4; mi++) {
#pragma unroll
    for (int ni = 0; ni < 4; ni++) {
      const int c = col0 + wc * 64 + ni * 16 + l15;
      const int rbase = row0 + wr * 64 + mi * 16 + lg * 4;
#pragma unroll
      for (int i = 0; i < 4; i++) {
        const int r = rbase + i;
        const float v = acc[mi][ni][i];
        if (MODE == 0) {
          const int which = c >> 10, cc = c & 1023;
          const int h = cc >> 6, dh = cc & 63;
          const int b = r >> 11, s = r & 2047;
          const size_t hb = (size_t)(b * NH + h);
          if (which == 0)
            O0[(hb * NS + s) * 64 + dh] = f2bf(v * 0.18033688011112042f);  // (1/8)*log2(e)
          else if (which == 1)
            O1[(hb * NS + s) * 64 + dh] = f2bf(v);
          else  // blocked V: [BH][t=s>>6][dh][s&63]
            O2[(((hb * 32 + (s >> 6)) * 64 + dh) * 64) + (s & 63)] = f2bf(v);
        } else {
          OF[(size_t)r * 1024 + c] = v;
        }
      }
    }
  }
#undef STAGE_TILE
}

// ---- stage one (K,V) tile pair (8KB each, contiguous) into wave-private LDS ----
// Inverse-rotation source swizzle (rule 21): LDS dest linear (wave-uniform base +
// lane*16); per-lane global src byte zs = row*128 + ((chunk - row&7)&7)*16 so that a
// reader using chunk' = (chunk + row&7)&7 sees the logical row-major tile.
__device__ __forceinline__ void stage_kv(const char* __restrict__ Kg,
                                         const char* __restrict__ Vg,
                                         char* kl, char* vl, int lane) {
#pragma unroll
  for (int j = 0; j < 8; ++j) {
    const int y = j * 1024 + lane * 16;
    const int r = y >> 7;
    const int zs = (r << 7) | ((((y >> 4) - r) & 7) << 4);
    gload_lds16(Kg + zs, kl + j * 1024);
    gload_lds16(Vg + zs, vl + j * 1024);
  }
}

// ---- one 32-row attention unit: rows [32gp, 32gp+32) of head bh ----
// Dual 16-row chains A/B (same tmax, unconditional -> ILP-2). No-max softmax
// (logits ~N(0,1), |s*log2e| << 127): P=exp2(s), masked -> 0; denominator via
// ones-MFMA. K/V from wave-private LDS tiles staged with coalesced global_load_lds;
// fragment reads use chunk-rotation swizzle (chunk' = (chunk + row&7)&7).
// vmcnt(0) asm (memory clobber) is REQUIRED: compiler cannot track the
// gload_lds -> ds_read dependency. lgkmcnt(0) asm before restaging is REQUIRED:
// reads must drain before the texture unit overwrites the buffers. The former
// sched_barrier(0)s are REMOVED (round-18 post-mortem: they pinned a full
// 16-read drain before any MFMA; the "memory" clobbers already order the
// memory ops, and MFMAs data-depend on the read outputs).
__device__ __forceinline__ void attn_unit(const uint16_t* __restrict__ Qh,
                                          const char* __restrict__ Kg,
                                          const char* __restrict__ Vg,
                                          uint16_t* __restrict__ Aout,
                                          int b, int h, int gp, int l15, int lg, int lane,
                                          char* kl, char* vl,
                                          uint16_t (*pX)[64][16]) {
  const int qbA = gp * 32;
  const int qbB = qbA + 16;
  const int tmax = gp >> 1;          // same last tile for both chains
  const int nfdA = (2 * gp) & 3;     // 0 or 2
  const int nfdB = nfdA + 1;

  // stage tile 0 (overlaps Q-fragment loads below)
  stage_kv(Kg, Vg, kl, vl, lane);

  const bf16x8 qfA0 = *(const bf16x8*)&Qh[(size_t)(qbA + l15) * 64 + lg * 8];
  const bf16x8 qfA1 = *(const bf16x8*)&Qh[(size_t)(qbA + l15) * 64 + 32 + lg * 8];
  const bf16x8 qfB0 = *(const bf16x8*)&Qh[(size_t)(qbB + l15) * 64 + lg * 8];
  const bf16x8 qfB1 = *(const bf16x8*)&Qh[(size_t)(qbB + l15) * 64 + 32 + lg * 8];

  const short one_bf = (short)0x3F80;  // bf16 1.0
  const bf16x8 ones = {one_bf, one_bf, one_bf, one_bf, one_bf, one_bf, one_bf, one_bf};

  const int rsw = l15 & 7;  // row&7 for both K rows (nf*16+l15) and V rows (df*16+l15)

  // P write col (u16): chunk' = (lg + (k>>2))&3 with (k>>2)&3 == l15>>2 (k=nf*16+l15)
  const int wcol = ((lg + (l15 >> 2)) & 3) * 4;
  // P tr-read per-lane swizzled addresses (round-16, verified)
  const int rr = l15 >> 2, cc0 = l15 & 3;
  const int rot = (2 * lg) & 3;
  const uint32_t pb = (uint32_t)(uintptr_t)&pX[0][0][0];
  const uint32_t addr0 = pb + (uint32_t)(lg * 256 + rr * 32 + (((cc0 + rot) & 3) * 8));
  const uint32_t addr1 = pb + (uint32_t)(lg * 256 + 128 + rr * 32 + (((cc0 + rot + 1) & 3) * 8));

  f32x4 oA[4], oB[4];
  f32x4 rsA = f32x4{0.f, 0.f, 0.f, 0.f};
  f32x4 rsB = f32x4{0.f, 0.f, 0.f, 0.f};
#pragma unroll
  for (int i = 0; i < 4; i++) {
    oA[i] = f32x4{0.f, 0.f, 0.f, 0.f};
    oB[i] = f32x4{0.f, 0.f, 0.f, 0.f};
  }

  for (int t = 0; t <= tmax; ++t) {
    // wait for this tile's staging to land (compiler can't see gload_lds->ds_read dep)
    asm volatile("s_waitcnt vmcnt(0)" ::: "memory");
    // read ALL K and V fragments into registers (rotation-swizzled ds_read_b128)
    bf16x8 kf[4][2], vf[4][2];
#pragma unroll
    for (int nf = 0; nf < 4; ++nf)
#pragma unroll
      for (int kk = 0; kk < 2; ++kk) {
        const int off = (nf * 16 + l15) * 128 + (((kk * 4 + lg) + rsw) & 7) * 16;
        kf[nf][kk] = *(const bf16x8*)(kl + off);
        vf[nf][kk] = *(const bf16x8*)(vl + off);
      }
    // drain reads before the texture unit may overwrite the buffers (correctness)
    asm volatile("s_waitcnt lgkmcnt(0)" ::: "memory");
    // prefetch next tile (frags are in regs; overwrites the buffers)
    if (t < tmax) stage_kv(Kg + (size_t)(t + 1) * 8192, Vg + (size_t)(t + 1) * 8192, kl, vl, lane);

    const int nfmA = (t == tmax) ? nfdA : 3;
    const int nfmB = (t == tmax) ? nfdB : 3;
#pragma unroll
    for (int nf = 0; nf < 4; ++nf) {
      if (nf <= nfmB) {
        f32x4 a = f32x4{0.f, 0.f, 0.f, 0.f};
        a = MFMA16(qfB0, kf[nf][0], a);
        a = MFMA16(qfB1, kf[nf][1], a);
        if (t == tmax && nf == nfdB) {  // chain-B diagonal fragment: mask col > row
#pragma unroll
          for (int i = 0; i < 4; i++)
            if (l15 > lg * 4 + i) a[i] = -1e30f;
        }
        {
          const float e0 = exp2f(a[0]), e1 = exp2f(a[1]);
          const float e2 = exp2f(a[2]), e3 = exp2f(a[3]);
          *(uint64_t*)&pX[1][nf * 16 + l15][wcol] =
              ((uint64_t)pk2(e2, e3) << 32) | pk2(e0, e1);
        }
        if (nf <= nfmA) {
          f32x4 c = f32x4{0.f, 0.f, 0.f, 0.f};
          c = MFMA16(qfA0, kf[nf][0], c);
          c = MFMA16(qfA1, kf[nf][1], c);
          if (t == tmax && nf == nfdA) {
#pragma unroll
            for (int i = 0; i < 4; i++)
              if (l15 > lg * 4 + i) c[i] = -1e30f;
          }
          const float e0 = exp2f(c[0]), e1 = exp2f(c[1]);
          const float e2 = exp2f(c[2]), e3 = exp2f(c[3]);
          *(uint64_t*)&pX[0][nf * 16 + l15][wcol] =
              ((uint64_t)pk2(e2, e3) << 32) | pk2(e0, e1);
        } else {
          *(uint64_t*)&pX[0][nf * 16 + l15][wcol] = 0ull;
        }
      } else {
        *(uint64_t*)&pX[0][nf * 16 + l15][wcol] = 0ull;
        *(uint64_t*)&pX[1][nf * 16 + l15][wcol] = 0ull;
      }
    }
    // transpose-read P fragments (waitcnt inside; MFMA data-depends on outputs)
    u32x2 a0, a1, a2, a3, b0, b1, b2, b3;
    asm volatile(
        "ds_read_b64_tr_b16 %0, %8\n\t"
        "ds_read_b64_tr_b16 %1, %9\n\t"
        "ds_read_b64_tr_b16 %2, %8 offset:1024\n\t"
        "ds_read_b64_tr_b16 %3, %9 offset:1024\n\t"
        "ds_read_b64_tr_b16 %4, %8 offset:2048\n\t"
        "ds_read_b64_tr_b16 %5, %9 offset:2048\n\t"
        "ds_read_b64_tr_b16 %6, %8 offset:3072\n\t"
        "ds_read_b64_tr_b16 %7, %9 offset:3072\n\t"
        "s_waitcnt lgkmcnt(0)"
        : "=&v"(a0), "=&v"(a1), "=&v"(a2), "=&v"(a3),
          "=&v"(b0), "=&v"(b1), "=&v"(b2), "=&v"(b3)
        : "v"(addr0), "v"(addr1)
        : "memory");
    union { u32x2 u2[2]; bf16x8 v8; } uA0, uA1, uB0, uB1;
    uA0.u2[0] = a0; uA0.u2[1] = a1;  // k = lg*8 + 0..7
    uA1.u2[0] = a2; uA1.u2[1] = a3;  // k = 32 + lg*8 + 0..7
    uB0.u2[0] = b0; uB0.u2[1] = b1;
    uB1.u2[0] = b2; uB1.u2[1] = b3;
    const bf16x8 paA0 = uA0.v8, paA1 = uA1.v8;
    const bf16x8 paB0 = uB0.v8, paB1 = uB1.v8;
    rsA = MFMA16(paA0, ones, rsA);
    rsA = MFMA16(paA1, ones, rsA);
    rsB = MFMA16(paB0, ones, rsB);
    rsB = MFMA16(paB1, ones, rsB);
#pragma unroll
    for (int df = 0; df < 4; ++df) {
      oA[df] = MFMA16(paA0, vf[df][0], oA[df]);
      oA[df] = MFMA16(paA1, vf[df][1], oA[df]);
      oB[df] = MFMA16(paB0, vf[df][0], oB[df]);
      oB[df] = MFMA16(paB1, vf[df][1], oB[df]);
    }
  }

#pragma unroll
  for (int df = 0; df < 4; ++df) {
#pragma unroll
    for (int i = 0; i < 4; i++) {
      const int qA = qbA + lg * 4 + i;
      const int qB = qbB + lg * 4 + i;
      Aout[((size_t)(b * NS + qA)) * 1024 + h * 64 + df * 16 + l15] = f2bf(oA[df][i] / rsA[i]);
      Aout[((size_t)(b * NS + qB)) * 1024 + h * 64 + df * 16 + l15] = f2bf(oB[df][i] / rsB[i]);
    }
  }
}

// ---------------- causal flash attention (wave = two sequential balanced units) ----------------
// grid 512 blocks x 4 waves = 2048 waves. Block decode: xcd = bid&7, sp = (bid>>3)&3,
// gblk = bid>>5; wave w -> g = gblk*4 + w (0..63).
// Wave runs unit (bh = (2sp)<<3|xcd, gp = g) then unit (bh = (2sp+1)<<3|xcd, gp = 63-g):
// total iterations = 33..34 for EVERY wave -> no stragglers; both heads on one XCD.
// LDS/wave: 8KB K-stage + 8KB V-stage + 4KB P = 20KB; 80KB/block -> 2 blocks/CU.
__global__ __launch_bounds__(256) void attn_fwd(const uint16_t* __restrict__ Q,
                                                const uint16_t* __restrict__ K,
                                                const uint16_t* __restrict__ Vt,
                                                uint16_t* __restrict__ Aout) {
  const int bid = blockIdx.x;
  const int xcd = bid & 7;
  const int sp = (bid >> 3) & 3;
  const int gblk = bid >> 5;  // 0..15

  const int w = threadIdx.x >> 6;
  const int lane = threadIdx.x & 63;
  const int l15 = lane & 15, lg = lane >> 4;
  const int g = gblk * 4 + w;  // 0..63

  __shared__ __align__(16) uint16_t plds[4][2][64][16];  // P buffers (16 KB)
  __shared__ __align__(16) char kstage[4][8192];         // K tiles  (32 KB)
  __shared__ __align__(16) char vstage[4][8192];         // V tiles  (32 KB)

  for (int seg = 0; seg < 2; ++seg) {
    const int slot = sp * 2 + seg;
    const int bh = (slot << 3) | xcd;
    const int gp = seg ? (63 - g) : g;
    const uint16_t* Qh = Q + (size_t)bh * (NS * 64);
    const char* Kg = (const char*)(K + (size_t)bh * (NS * 64));        // tiles at t*8192 B
    const char* Vg = (const char*)(Vt + (size_t)bh * (32 * 64 * 64));  // blocked tiles, t*8192 B
    attn_unit(Qh, Kg, Vg, Aout, bh >> 4, bh & 15, gp, l15, lg, lane,
              kstage[w], vstage[w], plds[w]);
  }
}

extern "C" void kernel_launch(void* const* d_in, const int* in_sizes, int n_in,
                              void* d_out, int out_size, void* d_ws, size_t ws_size,
                              hipStream_t stream) {
  const float* x = (const float*)d_in[0];
  const float* Wq = (const float*)d_in[1];
  const float* Wk = (const float*)d_in[2];
  const float* Wv = (const float*)d_in[3];
  const float* Wo = (const float*)d_in[4];
  float* out = (float*)d_out;

  char* ws = (char*)d_ws;
  uint16_t* xb = (uint16_t*)(ws);                        // 16 MB  (reused as attn buffer)
  uint16_t* Wt3 = (uint16_t*)(ws + (16u << 20));         // 6 MB   [3][1024][1024] (n-major)
  uint16_t* Wot = (uint16_t*)(ws + (22u << 20));         // 2 MB
  uint16_t* Qb = (uint16_t*)(ws + (24u << 20));          // 16 MB  [BH][S][64]
  uint16_t* Kb = (uint16_t*)(ws + (40u << 20));          // 16 MB  [BH][S][64]
  uint16_t* Vt = (uint16_t*)(ws + (56u << 20));          // 16 MB  blocked [BH][32][64][64]
  uint16_t* attn = xb;                                   // total 72 MB

  prep_kernel<<<12288, 256, 0, stream>>>(x, Wq, Wk, Wv, Wo, xb, Wt3, Wot);

  gemm_bt<0, 24><<<1536, 256, 0, stream>>>(xb, Wt3, Qb, Kb, Vt, nullptr);
  attn_fwd<<<512, 256, 0, stream>>>(Qb, Kb, Vt, attn);
  gemm_bt<1, 8><<<512, 256, 0, stream>>>(attn, Wot, nullptr, nullptr, nullptr, out);
}